// Round 13
// baseline (1643.881 us; speedup 1.0000x reference)
//
#include <hip/hip_runtime.h>

#define NN 32768
#define NE 1048576
#define BCAP 5120  // per-bucket capacity; mean 4096, sigma 64 -> 16 sigma headroom

typedef __bf16 bf16_t;
typedef __bf16 bf16x8 __attribute__((ext_vector_type(8)));
typedef __bf16 bf16x4 __attribute__((ext_vector_type(4)));
typedef float f32x4 __attribute__((ext_vector_type(4)));
typedef float f32x16 __attribute__((ext_vector_type(16)));
typedef unsigned int u32;
typedef unsigned short u16;

// ---------------- prologue: weight-frag prep | node encoder ----------------
// wfr layout (72 frags x 512):
//   0-23 : Weu1 as 32x32-A frags  (f = kstep*2 + tile, kstep<12)
//  24-31 : Weu2 as 32x32-A frags  (kstep<4)
//  32-39 : Wee2 as 32x32-A frags
//  40-47 : Wd1  as 32x32-A frags
//  48-63 : Wnu1 as 16x16 frags (kt<4, nt<4)
//  64-71 : Wnu2 as 16x16 frags
// 32x32-A frag: lane l holds W[k=kstep*16+(l>>5)*8+i][h=tile*32+(l&31)]
__global__ __launch_bounds__(256) void prep_encode_kernel(
    const float* __restrict__ Weu1, const float* __restrict__ Weu2,
    const float* __restrict__ Wee2, const float* __restrict__ Wd1,
    const float* __restrict__ Wnu1, const float* __restrict__ Wnu2,
    bf16_t* __restrict__ wfr,
    const float* __restrict__ nodes, const float* __restrict__ Wne1,
    const float* __restrict__ bne1, const float* __restrict__ Wne2,
    const float* __restrict__ bne2, bf16_t* __restrict__ n_bf) {
  const int b = blockIdx.x, tid = threadIdx.x;
  if (b < 144) {
    int idx = b * 256 + tid;  // < 36864
    int i = idx & 7, lane = (idx >> 3) & 63, f = idx >> 9;
    float v;
    if (f < 48) {
      const float* W;
      int fl;
      if (f < 24)      { W = Weu1; fl = f; }
      else if (f < 32) { W = Weu2; fl = f - 24; }
      else if (f < 40) { W = Wee2; fl = f - 32; }
      else             { W = Wd1;  fl = f - 40; }
      int ks = fl >> 1, t = fl & 1;
      int k = ks * 16 + ((lane >> 5) << 3) + i;
      int h = t * 32 + (lane & 31);
      v = W[k * 64 + h];
    } else if (f < 64) {
      int fl = f - 48, kt = fl >> 2, nt = fl & 3;
      v = Wnu1[(kt * 32 + ((lane >> 4) << 3) + i) * 64 + nt * 16 + (lane & 15)];
    } else {
      int fl = f - 64, kt = fl >> 2, nt = fl & 3;
      v = Wnu2[(kt * 32 + ((lane >> 4) << 3) + i) * 64 + nt * 16 + (lane & 15)];
    }
    wfr[idx] = (bf16_t)v;
  } else {
    __shared__ float hs[4][64];
    int wid = tid >> 6, k = tid & 63;
    int node = (b - 144) * 4 + wid;
    float x = nodes[node];
    hs[wid][k] = fmaxf(x * Wne1[k] + bne1[k], 0.0f);
    __syncthreads();
    float acc = bne2[k];
#pragma unroll 8
    for (int j = 0; j < 64; ++j) acc = fmaf(hs[wid][j], Wne2[j * 64 + k], acc);
    n_bf[(size_t)node * 64 + k] = (bf16_t)acc;
  }
}

// ---------------- CSR build, level 1: coarse 256-bucket scatter + absmax ----------------
__global__ __launch_bounds__(256) void coarse_kernel(
    const float* __restrict__ edges_init, const int* __restrict__ recv,
    float* __restrict__ norm, u32* __restrict__ ccur,
    u16* __restrict__ bkt_r, u32* __restrict__ bkt_o) {
  __shared__ u32 hist[256];
  __shared__ u32 base[256];
  __shared__ float mred[4];
  const int tid = threadIdx.x, lane = tid & 63, wid = tid >> 6;
  const int idx = blockIdx.x * 256 + tid;
  hist[tid] = 0;
  __syncthreads();
  int4 r = reinterpret_cast<const int4*>(recv)[idx];
  float4 v = reinterpret_cast<const float4*>(edges_init)[idx];
  float m = fmaxf(fmaxf(fabsf(v.x), fabsf(v.y)), fmaxf(fabsf(v.z), fabsf(v.w)));
#pragma unroll
  for (int off = 32; off > 0; off >>= 1) m = fmaxf(m, __shfl_xor(m, off, 64));
  if (lane == 0) mred[wid] = m;
  atomicAdd(&hist[r.x >> 7], 1u);
  atomicAdd(&hist[r.y >> 7], 1u);
  atomicAdd(&hist[r.z >> 7], 1u);
  atomicAdd(&hist[r.w >> 7], 1u);
  __syncthreads();
  if (tid == 0) {
    float mm = fmaxf(fmaxf(mred[0], mred[1]), fmaxf(mred[2], mred[3]));
    atomicMax(reinterpret_cast<u32*>(norm), __float_as_uint(mm));
  }
  u32 h = hist[tid];
  if (h) base[tid] = atomicAdd(&ccur[tid], h);
  hist[tid] = 0;  // reuse as block-local cursor
  __syncthreads();
  const int e0 = idx * 4;
  int rv4[4] = {r.x, r.y, r.z, r.w};
#pragma unroll
  for (int q = 0; q < 4; ++q) {
    int rv = rv4[q], bk = rv >> 7;
    u32 loc = atomicAdd(&hist[bk], 1u);
    u32 pos = (u32)bk * BCAP + base[bk] + loc;
    bkt_r[pos] = (u16)rv;
    bkt_o[pos] = (u32)(e0 + q);
  }
}

__global__ __launch_bounds__(256) void scan256_kernel(const u32* __restrict__ ccur,
                                                      u32* __restrict__ bbase,
                                                      int* __restrict__ row_ptr) {
  __shared__ u32 s[256];
  const int tid = threadIdx.x;
  s[tid] = ccur[tid];
  __syncthreads();
  if (tid == 0) {
    u32 run = 0;
    for (int j = 0; j < 256; ++j) {
      u32 c = s[j];
      s[j] = run;
      run += c;
    }
    row_ptr[NN] = (int)run;
  }
  __syncthreads();
  bbase[tid] = s[tid];
}

__global__ __launch_bounds__(1024) void bucket_kernel(
    const u32* __restrict__ ccur, const u32* __restrict__ bbase,
    const u16* __restrict__ bkt_r, const u32* __restrict__ bkt_o,
    const int* __restrict__ senders, const float* __restrict__ edges_init,
    int* __restrict__ row_ptr, int* __restrict__ col_idx,
    int* __restrict__ s_perm, int* __restrict__ r_perm, float* __restrict__ x_perm) {
  __shared__ u32 hist[128];
  __shared__ u32 cur[128];
  const int b = blockIdx.x, tid = threadIdx.x;
  const u32 sz = ccur[b], bb = bbase[b];
  if (tid < 128) hist[tid] = 0;
  __syncthreads();
  for (u32 i = tid; i < sz; i += 1024) atomicAdd(&hist[bkt_r[(u32)b * BCAP + i] & 127], 1u);
  __syncthreads();
  if (tid == 0) {
    u32 run = 0;
    for (int j = 0; j < 128; ++j) {
      u32 c = hist[j];
      hist[j] = run;
      cur[j] = run;
      run += c;
    }
  }
  __syncthreads();
  if (tid < 128) row_ptr[b * 128 + tid] = (int)(bb + hist[tid]);
  for (u32 i = tid; i < sz; i += 1024) {
    int rv = (int)bkt_r[(u32)b * BCAP + i];
    int o = (int)bkt_o[(u32)b * BCAP + i];
    u32 loc = atomicAdd(&cur[rv & 127], 1u);
    u32 pos = bb + loc;
    col_idx[pos] = o;
    s_perm[pos] = senders[o];
    r_perm[pos] = rv;
    x_perm[pos] = edges_init[o];
  }
}

// ---------------- mega edge kernel (32x32x16 MFMA, 32 edges/wave) ----------------
// MODE 0=encode+round0, 1=mid, 2=round4+decode. 384-thread blocks (6 waves), grid 512
// -> 2 blocks/CU by LDS (69KB), 12 waves/CU (3/SIMD by VGPR). No occupancy clamp
// (R4/R10: clamps spill the ~150-reg pipeline state, 6x loss).
// A-frag (W): lane holds h=tile*32+(l&31), k=(l>>5)*8+i. B-frag (data): edge=(l&31),
// same k. C/D: col(edge)=lane&31, row(h)=(reg&3)+8*(reg>>2)+4*(lane>>5) [per guide].
template <int MODE>
__global__ __launch_bounds__(384) void edge_update_kernel(
    bf16_t* __restrict__ e, const bf16_t* __restrict__ n_bf,
    const int* __restrict__ col_idx,
    const int* __restrict__ s_perm, const int* __restrict__ r_perm,
    const float* __restrict__ x_perm,
    const bf16_t* __restrict__ wfr,
    const float* __restrict__ beu1, const float* __restrict__ beu2,
    const float* __restrict__ Wee1, const float* __restrict__ bee1,
    const float* __restrict__ bee2, const float* __restrict__ norm_p,
    const float* __restrict__ bd1, const float* __restrict__ Wd2,
    const float* __restrict__ bd2_p, const float* __restrict__ alpha_p,
    float* __restrict__ out) {
  __shared__ alignas(16) bf16_t wstage[40 * 512];  // [W1A 0-23][W2A 24-31][Wee2A|Wd1A 32-39]
  __shared__ alignas(16) bf16_t tr[6][32][72];     // per-wave 32x64 transpose (pitch 72)
  __shared__ alignas(16) float fconst[448];        // Wee1|bee1|bee2|bd1|Wd2|beu1|beu2
  const int tid = threadIdx.x, lane = tid & 63, wid = tid >> 6;
  const int e31 = lane & 31, hi = lane >> 5;

  // stage weights: 40 frags x 1KB = 2560 chunks of 16B
#pragma unroll
  for (int j = 0; j < 7; ++j) {
    int c = j * 384 + tid;
    if (c < 2560) {
      int slot = c >> 6, within = c & 63;
      int sf = (slot < 32) ? slot : (MODE == 2 ? slot + 8 : slot);
      *reinterpret_cast<bf16x8*>(wstage + slot * 512 + within * 8) =
          *reinterpret_cast<const bf16x8*>(wfr + (size_t)sf * 512 + within * 8);
    }
  }
  for (int c = tid; c < 448; c += 384) {
    float v;
    if (c < 64)       v = Wee1[c];
    else if (c < 128) v = bee1[c - 64];
    else if (c < 192) v = bee2[c - 128];
    else if (c < 256) v = bd1[c - 192];
    else if (c < 320) v = Wd2[c - 256];
    else if (c < 384) v = beu1[c - 320];
    else              v = beu2[c - 384];
    fconst[c] = v;
  }
  __syncthreads();  // only block-wide barrier

  float invn = 0.f;
  if constexpr (MODE == 0) invn = 1.0f / *norm_p;
  float nrm = 0.f, alp = 0.f, b2s = 0.f;
  if constexpr (MODE == 2) { nrm = *norm_p; alp = *alpha_p; b2s = *bd2_p; }

  // XCD-aware block swizzle (gridDim.x % 8 == 0)
  const int nb = gridDim.x, cpx = nb >> 3;
  const int bs = (blockIdx.x & 7) * cpx + (blockIdx.x >> 3);
  const int NWAVE = nb * 6;
  const int NG = NE / 32;
  const int g0 = bs * 6 + wid;

  auto LDSCAL = [&](int g, int& s, int& r, int& o, float& px) {
    int row = g * 32 + e31;
    s = s_perm[row];
    r = r_perm[row];
    if constexpr (MODE == 2) o = col_idx[row];
    if constexpr (MODE != 1) px = x_perm[row];
  };
  // d[0..3]=e-frags (MODE!=0), d[4..7]=n_s, d[8..11]=n_r; frag j: elems j*16+hi*8..+7
  auto LDDATA = [&](int g, int s, int r, bf16x8* d) {
    if constexpr (MODE != 0) {
      const bf16_t* er = e + (size_t)(g * 32 + e31) * 64 + hi * 8;
#pragma unroll
      for (int j = 0; j < 4; ++j) d[j] = *reinterpret_cast<const bf16x8*>(er + j * 16);
    }
    const bf16_t* sp = n_bf + (size_t)s * 64 + hi * 8;
#pragma unroll
    for (int j = 0; j < 4; ++j) d[4 + j] = *reinterpret_cast<const bf16x8*>(sp + j * 16);
    const bf16_t* rp = n_bf + (size_t)r * 64 + hi * 8;
#pragma unroll
    for (int j = 0; j < 4; ++j) d[8 + j] = *reinterpret_cast<const bf16x8*>(rp + j * 16);
  };

  int sA = 0, rA = 0, oA = 0, sB = 0, rB = 0, oB = 0;
  float pxA = 0.f, pxB = 0.f;
  bf16x8 dA[12], dB[12];
  if (g0 < NG) {
    LDSCAL(g0, sA, rA, oA, pxA);
    LDDATA(g0, sA, rA, dA);
    int g1 = g0 + NWAVE;
    if (g1 < NG) LDSCAL(g1, sB, rB, oB, pxB);
  }

  for (int g = g0; g < NG; g += NWAVE) {
    const int gB = g + NWAVE, gC = g + 2 * NWAVE;
    int sC = 0, rC = 0, oC = 0;
    float pxC = 0.f;
    if (gB < NG) {
      LDDATA(gB, sB, rB, dB);
      if (gC < NG) LDSCAL(gC, sC, rC, oC, pxC);
    }

    // === compute group g (32 edges) ===
    bf16x8 ce[4];
    if constexpr (MODE == 0) {
      // encoder: h B-frags from scalar x, e0 = h @ Wee2 + bee2 (no relu on output)
      float xv = pxA * invn;
      bf16x8 hb[4];
#pragma unroll
      for (int st = 0; st < 4; ++st) {
#pragma unroll
        for (int t2 = 0; t2 < 2; ++t2) {
          f32x4 w = *reinterpret_cast<const f32x4*>(&fconst[st * 16 + hi * 8 + t2 * 4]);
          f32x4 bb = *reinterpret_cast<const f32x4*>(&fconst[64 + st * 16 + hi * 8 + t2 * 4]);
#pragma unroll
          for (int jj = 0; jj < 4; ++jj)
            hb[st][t2 * 4 + jj] = (bf16_t)fmaxf(fmaf(xv, w[jj], bb[jj]), 0.0f);
        }
      }
      f32x16 ae0, ae1;
#pragma unroll
      for (int q = 0; q < 4; ++q) {
        f32x4 b0 = *reinterpret_cast<const f32x4*>(&fconst[128 + q * 8 + hi * 4]);
        f32x4 b1 = *reinterpret_cast<const f32x4*>(&fconst[128 + 32 + q * 8 + hi * 4]);
#pragma unroll
        for (int jj = 0; jj < 4; ++jj) { ae0[q * 4 + jj] = b0[jj]; ae1[q * 4 + jj] = b1[jj]; }
      }
#pragma unroll
      for (int ks = 0; ks < 4; ++ks) {
        bf16x8 w0 = *reinterpret_cast<const bf16x8*>(wstage + (32 + ks * 2 + 0) * 512 + lane * 8);
        bf16x8 w1 = *reinterpret_cast<const bf16x8*>(wstage + (32 + ks * 2 + 1) * 512 + lane * 8);
        ae0 = __builtin_amdgcn_mfma_f32_32x32x16_bf16(w0, hb[ks], ae0, 0, 0, 0);
        ae1 = __builtin_amdgcn_mfma_f32_32x32x16_bf16(w1, hb[ks], ae1, 0, 0, 0);
      }
#pragma unroll
      for (int q = 0; q < 4; ++q) {
        bf16x4 p0, p1;
#pragma unroll
        for (int jj = 0; jj < 4; ++jj) {
          p0[jj] = (bf16_t)ae0[q * 4 + jj];
          p1[jj] = (bf16_t)ae1[q * 4 + jj];
        }
        *reinterpret_cast<bf16x4*>(&tr[wid][e31][q * 8 + hi * 4]) = p0;
        *reinterpret_cast<bf16x4*>(&tr[wid][e31][32 + q * 8 + hi * 4]) = p1;
      }
#pragma unroll
      for (int st = 0; st < 4; ++st)
        ce[st] = *reinterpret_cast<const bf16x8*>(&tr[wid][e31][st * 16 + hi * 8]);
    } else {
#pragma unroll
      for (int st = 0; st < 4; ++st) ce[st] = dA[st];
    }

    // layer 1: [32 edges x 192] @ Weu1, D^T[h][edge], 2 h-tiles
    f32x16 a0, a1;
#pragma unroll
    for (int q = 0; q < 4; ++q) {
      f32x4 b0 = *reinterpret_cast<const f32x4*>(&fconst[320 + q * 8 + hi * 4]);
      f32x4 b1 = *reinterpret_cast<const f32x4*>(&fconst[320 + 32 + q * 8 + hi * 4]);
#pragma unroll
      for (int jj = 0; jj < 4; ++jj) { a0[q * 4 + jj] = b0[jj]; a1[q * 4 + jj] = b1[jj]; }
    }
#pragma unroll
    for (int ks = 0; ks < 12; ++ks) {
      bf16x8 bop = (ks < 4) ? ce[ks] : dA[ks];
      bf16x8 w0 = *reinterpret_cast<const bf16x8*>(wstage + (ks * 2 + 0) * 512 + lane * 8);
      bf16x8 w1 = *reinterpret_cast<const bf16x8*>(wstage + (ks * 2 + 1) * 512 + lane * 8);
      a0 = __builtin_amdgcn_mfma_f32_32x32x16_bf16(w0, bop, a0, 0, 0, 0);
      a1 = __builtin_amdgcn_mfma_f32_32x32x16_bf16(w1, bop, a1, 0, 0, 0);
    }

    // relu -> tr -> h B-frags
#pragma unroll
    for (int q = 0; q < 4; ++q) {
      bf16x4 p0, p1;
#pragma unroll
      for (int jj = 0; jj < 4; ++jj) {
        p0[jj] = (bf16_t)fmaxf(a0[q * 4 + jj], 0.0f);
        p1[jj] = (bf16_t)fmaxf(a1[q * 4 + jj], 0.0f);
      }
      *reinterpret_cast<bf16x4*>(&tr[wid][e31][q * 8 + hi * 4]) = p0;
      *reinterpret_cast<bf16x4*>(&tr[wid][e31][32 + q * 8 + hi * 4]) = p1;
    }
    bf16x8 hh[4];
#pragma unroll
    for (int st = 0; st < 4; ++st)
      hh[st] = *reinterpret_cast<const bf16x8*>(&tr[wid][e31][st * 16 + hi * 8]);

    // layer 2: [32 x 64] @ Weu2
    f32x16 c0, c1;
#pragma unroll
    for (int q = 0; q < 4; ++q) {
      f32x4 b0 = *reinterpret_cast<const f32x4*>(&fconst[384 + q * 8 + hi * 4]);
      f32x4 b1 = *reinterpret_cast<const f32x4*>(&fconst[384 + 32 + q * 8 + hi * 4]);
#pragma unroll
      for (int jj = 0; jj < 4; ++jj) { c0[q * 4 + jj] = b0[jj]; c1[q * 4 + jj] = b1[jj]; }
    }
#pragma unroll
    for (int ks = 0; ks < 4; ++ks) {
      bf16x8 w0 = *reinterpret_cast<const bf16x8*>(wstage + (24 + ks * 2 + 0) * 512 + lane * 8);
      bf16x8 w1 = *reinterpret_cast<const bf16x8*>(wstage + (24 + ks * 2 + 1) * 512 + lane * 8);
      c0 = __builtin_amdgcn_mfma_f32_32x32x16_bf16(w0, hh[ks], c0, 0, 0, 0);
      c1 = __builtin_amdgcn_mfma_f32_32x32x16_bf16(w1, hh[ks], c1, 0, 0, 0);
    }

    if constexpr (MODE == 2) {
      // decoder: e_new -> tr -> B-frags; ad = relu(e_new @ Wd1 + bd1); dot Wd2
#pragma unroll
      for (int q = 0; q < 4; ++q) {
        bf16x4 p0, p1;
#pragma unroll
        for (int jj = 0; jj < 4; ++jj) {
          p0[jj] = (bf16_t)c0[q * 4 + jj];
          p1[jj] = (bf16_t)c1[q * 4 + jj];
        }
        *reinterpret_cast<bf16x4*>(&tr[wid][e31][q * 8 + hi * 4]) = p0;
        *reinterpret_cast<bf16x4*>(&tr[wid][e31][32 + q * 8 + hi * 4]) = p1;
      }
      bf16x8 eb[4];
#pragma unroll
      for (int st = 0; st < 4; ++st)
        eb[st] = *reinterpret_cast<const bf16x8*>(&tr[wid][e31][st * 16 + hi * 8]);
      f32x16 ad0, ad1;
#pragma unroll
      for (int q = 0; q < 4; ++q) {
        f32x4 b0 = *reinterpret_cast<const f32x4*>(&fconst[192 + q * 8 + hi * 4]);
        f32x4 b1 = *reinterpret_cast<const f32x4*>(&fconst[192 + 32 + q * 8 + hi * 4]);
#pragma unroll
        for (int jj = 0; jj < 4; ++jj) { ad0[q * 4 + jj] = b0[jj]; ad1[q * 4 + jj] = b1[jj]; }
      }
#pragma unroll
      for (int ks = 0; ks < 4; ++ks) {
        bf16x8 w0 = *reinterpret_cast<const bf16x8*>(wstage + (32 + ks * 2 + 0) * 512 + lane * 8);
        bf16x8 w1 = *reinterpret_cast<const bf16x8*>(wstage + (32 + ks * 2 + 1) * 512 + lane * 8);
        ad0 = __builtin_amdgcn_mfma_f32_32x32x16_bf16(w0, eb[ks], ad0, 0, 0, 0);
        ad1 = __builtin_amdgcn_mfma_f32_32x32x16_bf16(w1, eb[ks], ad1, 0, 0, 0);
      }
      float sdot = 0.0f;
#pragma unroll
      for (int q = 0; q < 4; ++q) {
        f32x4 w0 = *reinterpret_cast<const f32x4*>(&fconst[256 + q * 8 + hi * 4]);
        f32x4 w1 = *reinterpret_cast<const f32x4*>(&fconst[256 + 32 + q * 8 + hi * 4]);
#pragma unroll
        for (int jj = 0; jj < 4; ++jj) {
          sdot = fmaf(fmaxf(ad0[q * 4 + jj], 0.0f), w0[jj], sdot);
          sdot = fmaf(fmaxf(ad1[q * 4 + jj], 0.0f), w1[jj], sdot);
        }
      }
      sdot += __shfl_xor(sdot, 32, 64);
      if (hi == 0) {
        float dv = sdot + b2s;
        out[oA] = (rA >= sA) ? fmaf(alp * nrm, dv, pxA) : 0.0f;
      }
    } else {
      // pack e_new -> tr -> full-line stores (4x 16B/lane contiguous)
#pragma unroll
      for (int q = 0; q < 4; ++q) {
        bf16x4 p0, p1;
#pragma unroll
        for (int jj = 0; jj < 4; ++jj) {
          p0[jj] = (bf16_t)c0[q * 4 + jj];
          p1[jj] = (bf16_t)c1[q * 4 + jj];
        }
        *reinterpret_cast<bf16x4*>(&tr[wid][e31][q * 8 + hi * 4]) = p0;
        *reinterpret_cast<bf16x4*>(&tr[wid][e31][32 + q * 8 + hi * 4]) = p1;
      }
#pragma unroll
      for (int j = 0; j < 4; ++j) {
        int p = j * 1024 + lane * 16;
        int rrow = p >> 7, cb = p & 127;
        bf16x8 v = *reinterpret_cast<const bf16x8*>(
            reinterpret_cast<const char*>(&tr[wid][0][0]) + rrow * 144 + cb);
        *reinterpret_cast<bf16x8*>(
            reinterpret_cast<char*>(e) + (size_t)(g * 32 + rrow) * 128 + cb) = v;
      }
    }

    // rotate pipeline state
    sA = sB; rA = rB; oA = oB; pxA = pxB;
#pragma unroll
    for (int i = 0; i < 12; ++i) dA[i] = dB[i];
    sB = sC; rB = rC; oB = oC; pxB = pxC;
  }
}

// ---------------- agg: full-occupancy streaming segment-sum ----------------
__global__ __launch_bounds__(256) void agg_kernel(const bf16_t* __restrict__ e,
                                                  const int* __restrict__ row_ptr,
                                                  bf16_t* __restrict__ agg) {
  const int lane = threadIdx.x & 63, wid = threadIdx.x >> 6;
  const int rsub = lane >> 3;
  const int gw = blockIdx.x * 4 + wid, NWV = gridDim.x * 4;
  for (int node = gw; node < NN; node += NWV) {
    const int p0 = row_ptr[node], cnt = row_ptr[node + 1] - p0;
    float a[8] = {0, 0, 0, 0, 0, 0, 0, 0};
    const bf16x8* bb = reinterpret_cast<const bf16x8*>(e + (size_t)p0 * 64) + lane;
    const int nchunk = (cnt + 7) >> 3;
    int c = 0;
    for (; c + 4 <= nchunk; c += 4) {
      bf16x8 v0 = bb[(size_t)(c + 0) * 64];
      bf16x8 v1 = bb[(size_t)(c + 1) * 64];
      bf16x8 v2 = bb[(size_t)(c + 2) * 64];
      bf16x8 v3 = bb[(size_t)(c + 3) * 64];
      {
#pragma unroll
        for (int i = 0; i < 8; ++i) a[i] += (float)v0[i];
#pragma unroll
        for (int i = 0; i < 8; ++i) a[i] += (float)v1[i];
#pragma unroll
        for (int i = 0; i < 8; ++i) a[i] += (float)v2[i];
      }
      if ((c + 3) * 8 + rsub < cnt) {
#pragma unroll
        for (int i = 0; i < 8; ++i) a[i] += (float)v3[i];
      }
    }
    for (; c < nchunk; ++c) {
      bf16x8 v = bb[(size_t)c * 64];
      if (c * 8 + rsub < cnt) {
#pragma unroll
        for (int i = 0; i < 8; ++i) a[i] += (float)v[i];
      }
    }
#pragma unroll
    for (int i = 0; i < 8; ++i) {
      a[i] += __shfl_xor(a[i], 8, 64);
      a[i] += __shfl_xor(a[i], 16, 64);
      a[i] += __shfl_xor(a[i], 32, 64);
    }
    if (lane < 8) {
      bf16x8 pk;
#pragma unroll
      for (int i = 0; i < 8; ++i) pk[i] = (bf16_t)a[i];
      *reinterpret_cast<bf16x8*>(agg + (size_t)node * 64 + lane * 8) = pk;
    }
  }
}

// ---------------- node MLP via 16x16 MFMA (16 nodes per wave-task) ----------------
__global__ __launch_bounds__(256) void node_mlp_kernel(
    const bf16_t* __restrict__ agg, const bf16_t* __restrict__ wfr,
    const float* __restrict__ bnu1, const float* __restrict__ bnu2,
    bf16_t* __restrict__ n_bf) {
  __shared__ alignas(16) bf16_t w2s[8 * 512];   // Wnu2 frags (64-71), 8 KB
  __shared__ alignas(16) bf16_t xb[4][16][72];  // per-wave transpose buffer
  const int tid = threadIdx.x, lane = tid & 63, wid = tid >> 6;
  const int l15 = lane & 15, lg = lane >> 4;

  bf16x8 W1r[16];
#pragma unroll
  for (int f = 0; f < 16; ++f)
    W1r[f] = *reinterpret_cast<const bf16x8*>(wfr + (size_t)(48 + f) * 512 + lane * 8);
#pragma unroll
  for (int j = 0; j < 2; ++j)
    reinterpret_cast<bf16x8*>(w2s)[j * 256 + tid] =
        reinterpret_cast<const bf16x8*>(wfr + (size_t)64 * 512)[j * 256 + tid];
  __syncthreads();

  f32x4 b1q[4], b2q[4];
#pragma unroll
  for (int nt = 0; nt < 4; ++nt) {
    b1q[nt] = *reinterpret_cast<const f32x4*>(bnu1 + nt * 16 + lg * 4);
    b2q[nt] = *reinterpret_cast<const f32x4*>(bnu2 + nt * 16 + lg * 4);
  }

  const int NT = NN / 16;
  for (int task = blockIdx.x * 4 + wid; task < NT; task += gridDim.x * 4) {
    const int base = task * 16;
    bf16x8 xn0 = *reinterpret_cast<const bf16x8*>(n_bf + (size_t)(base + l15) * 64 + lg * 8);
    bf16x8 xn1 = *reinterpret_cast<const bf16x8*>(n_bf + (size_t)(base + l15) * 64 + 32 + lg * 8);
    bf16x8 xa0 = *reinterpret_cast<const bf16x8*>(agg + (size_t)(base + l15) * 64 + lg * 8);
    bf16x8 xa1 = *reinterpret_cast<const bf16x8*>(agg + (size_t)(base + l15) * 64 + 32 + lg * 8);
    f32x4 acc[4];
#pragma unroll
    for (int nt = 0; nt < 4; ++nt) acc[nt] = b1q[nt];
#pragma unroll
    for (int kt = 0; kt < 4; ++kt) {
      bf16x8 x = (kt == 0) ? xn0 : (kt == 1) ? xn1 : (kt == 2) ? xa0 : xa1;
#pragma unroll
      for (int nt = 0; nt < 4; ++nt)
        acc[nt] = __builtin_amdgcn_mfma_f32_16x16x32_bf16(W1r[kt * 4 + nt], x, acc[nt], 0, 0, 0);
    }
#pragma unroll
    for (int nt = 0; nt < 4; ++nt) {
      bf16x4 pk;
#pragma unroll
      for (int r = 0; r < 4; ++r) pk[r] = (bf16_t)fmaxf(acc[nt][r], 0.0f);
      *reinterpret_cast<bf16x4*>(&xb[wid][l15][nt * 16 + lg * 4]) = pk;
    }
    bf16x8 hh0 = *reinterpret_cast<const bf16x8*>(&xb[wid][l15][lg * 8]);
    bf16x8 hh1 = *reinterpret_cast<const bf16x8*>(&xb[wid][l15][32 + lg * 8]);
    f32x4 acc2[4];
#pragma unroll
    for (int nt = 0; nt < 4; ++nt) acc2[nt] = b2q[nt];
#pragma unroll
    for (int kt = 0; kt < 2; ++kt)
#pragma unroll
      for (int nt = 0; nt < 4; ++nt) {
        bf16x8 w = *reinterpret_cast<const bf16x8*>(w2s + (kt * 4 + nt) * 512 + lane * 8);
        acc2[nt] = __builtin_amdgcn_mfma_f32_16x16x32_bf16(w, kt ? hh1 : hh0, acc2[nt], 0, 0, 0);
      }
#pragma unroll
    for (int nt = 0; nt < 4; ++nt) {
      bf16x4 pk;
#pragma unroll
      for (int r = 0; r < 4; ++r) pk[r] = (bf16_t)acc2[nt][r];
      *reinterpret_cast<bf16x4*>(n_bf + (size_t)(base + l15) * 64 + nt * 16 + lg * 4) = pk;
    }
  }
}

extern "C" void kernel_launch(void* const* d_in, const int* in_sizes, int n_in,
                              void* d_out, int out_size, void* d_ws, size_t ws_size,
                              hipStream_t stream) {
  const float* nodes      = (const float*)d_in[0];
  const float* edges_init = (const float*)d_in[1];
  const int*   receivers  = (const int*)d_in[2];
  const int*   senders    = (const int*)d_in[3];
  const float* Wne1 = (const float*)d_in[4];
  const float* bne1 = (const float*)d_in[5];
  const float* Wne2 = (const float*)d_in[6];
  const float* bne2 = (const float*)d_in[7];
  const float* Wee1 = (const float*)d_in[8];
  const float* bee1 = (const float*)d_in[9];
  const float* Wee2 = (const float*)d_in[10];
  const float* bee2 = (const float*)d_in[11];
  const float* Weu1 = (const float*)d_in[12];
  const float* beu1 = (const float*)d_in[13];
  const float* Weu2 = (const float*)d_in[14];
  const float* beu2 = (const float*)d_in[15];
  const float* Wnu1 = (const float*)d_in[16];
  const float* bnu1 = (const float*)d_in[17];
  const float* Wnu2 = (const float*)d_in[18];
  const float* bnu2 = (const float*)d_in[19];
  const float* Wd1  = (const float*)d_in[20];
  const float* bd1  = (const float*)d_in[21];
  const float* Wd2  = (const float*)d_in[22];
  const float* bd2  = (const float*)d_in[23];
  const float* alpha = (const float*)d_in[24];
  float* out = (float*)d_out;
  (void)in_sizes; (void)n_in; (void)out_size; (void)ws_size;

  char* ws = (char*)d_ws;
  size_t off = 0;
  auto alloc = [&](size_t bytes) -> void* {
    void* p = ws + off;
    off = (off + bytes + 255) & ~(size_t)255;
    return p;
  };
  float*  norm    = (float*)alloc(4);
  u32*    ccur    = (u32*)alloc(sizeof(u32) * 256);
  u32*    bbase   = (u32*)alloc(sizeof(u32) * 256);
  int*    row_ptr = (int*)alloc(sizeof(int) * (NN + 1));
  u16*    bkt_r   = (u16*)alloc(sizeof(u16) * 256 * BCAP);
  u32*    bkt_o   = (u32*)alloc(sizeof(u32) * 256 * BCAP);
  int*    col_idx = (int*)alloc(sizeof(int) * NE);
  int*    s_perm  = (int*)alloc(sizeof(int) * NE);
  int*    r_perm  = (int*)alloc(sizeof(int) * NE);
  float*  x_perm  = (float*)alloc(sizeof(float) * NE);
  bf16_t* n_bf    = (bf16_t*)alloc(sizeof(bf16_t) * (size_t)NN * 64);
  bf16_t* agg     = (bf16_t*)alloc(sizeof(bf16_t) * (size_t)NN * 64);
  bf16_t* e_buf   = (bf16_t*)alloc(sizeof(bf16_t) * (size_t)NE * 64 + 4096);
  bf16_t* wfr     = (bf16_t*)alloc(sizeof(bf16_t) * 72 * 512);

  hipMemsetAsync(norm, 0, 4, stream);
  hipMemsetAsync(ccur, 0, sizeof(u32) * 256, stream);

  prep_encode_kernel<<<8336, 256, 0, stream>>>(Weu1, Weu2, Wee2, Wd1, Wnu1, Wnu2, wfr,
                                               nodes, Wne1, bne1, Wne2, bne2, n_bf);
  coarse_kernel<<<1024, 256, 0, stream>>>(edges_init, receivers, norm, ccur, bkt_r, bkt_o);
  scan256_kernel<<<1, 256, 0, stream>>>(ccur, bbase, row_ptr);
  bucket_kernel<<<256, 1024, 0, stream>>>(ccur, bbase, bkt_r, bkt_o, senders, edges_init,
                                          row_ptr, col_idx, s_perm, r_perm, x_perm);

  edge_update_kernel<0><<<512, 384, 0, stream>>>(
      e_buf, n_bf, col_idx, s_perm, r_perm, x_perm, wfr, beu1, beu2,
      Wee1, bee1, bee2, norm, bd1, Wd2, bd2, alpha, out);
  for (int t = 1; t <= 4; ++t) {
    agg_kernel<<<2048, 256, 0, stream>>>(e_buf, row_ptr, agg);
    node_mlp_kernel<<<512, 256, 0, stream>>>(agg, wfr, bnu1, bnu2, n_bf);
    if (t < 4)
      edge_update_kernel<1><<<512, 384, 0, stream>>>(
          e_buf, n_bf, col_idx, s_perm, r_perm, x_perm, wfr, beu1, beu2,
          Wee1, bee1, bee2, norm, bd1, Wd2, bd2, alpha, out);
    else
      edge_update_kernel<2><<<512, 384, 0, stream>>>(
          e_buf, n_bf, col_idx, s_perm, r_perm, x_perm, wfr, beu1, beu2,
          Wee1, bee1, bee2, norm, bd1, Wd2, bd2, alpha, out);
  }
}

// Round 14
// 606.156 us; speedup vs baseline: 2.7120x; 2.7120x over previous
//
#include <hip/hip_runtime.h>

#define NN 32768
#define NE 1048576
#define BCAP 5120  // per-bucket capacity; mean 4096, sigma 64 -> 16 sigma headroom

typedef __bf16 bf16_t;
typedef __bf16 bf16x8 __attribute__((ext_vector_type(8)));
typedef __bf16 bf16x4 __attribute__((ext_vector_type(4)));
typedef float f32x4 __attribute__((ext_vector_type(4)));
typedef unsigned int u32;
typedef unsigned short u16;

// ---------------- prologue: weight-frag prep | node encoder ----------------
// wfr layout (64 frags x 512), all 16x16 frags (lane: dim=nt*16+(l&15), k=kt*32+(l>>4)*8+i):
//   0-23 Weu1 | 24-31 Weu2 | 32-39 Wee2 | 40-47 Wd1 | 48-55 Wnu1(2H->H, kt<4 packs K=128) |
//   wait: Wnu1 K=128 -> kt<4, nt<4 = 16 frags: 48-63 | 64-71 Wnu2
__global__ __launch_bounds__(256) void prep_encode_kernel(
    const float* __restrict__ Weu1, const float* __restrict__ Weu2,
    const float* __restrict__ Wee2, const float* __restrict__ Wd1,
    const float* __restrict__ Wnu1, const float* __restrict__ Wnu2,
    bf16_t* __restrict__ wfr,
    const float* __restrict__ nodes, const float* __restrict__ Wne1,
    const float* __restrict__ bne1, const float* __restrict__ Wne2,
    const float* __restrict__ bne2, bf16_t* __restrict__ n_bf) {
  const int b = blockIdx.x, tid = threadIdx.x;
  if (b < 144) {
    int idx = b * 256 + tid;  // < 36864 = 72 frags
    int i = idx & 7, lane = (idx >> 3) & 63, f = idx >> 9;
    const float* W;
    int fl;
    if (f < 24)      { W = Weu1; fl = f; }
    else if (f < 32) { W = Weu2; fl = f - 24; }
    else if (f < 40) { W = Wee2; fl = f - 32; }
    else if (f < 48) { W = Wd1;  fl = f - 40; }
    else if (f < 64) { W = Wnu1; fl = f - 48; }
    else             { W = Wnu2; fl = f - 64; }
    int kt = fl >> 2, nt = fl & 3;
    int k = kt * 32 + ((lane >> 4) << 3) + i;
    int col = nt * 16 + (lane & 15);
    wfr[idx] = (bf16_t)W[k * 64 + col];
  } else {
    __shared__ float hs[4][64];
    int wid = tid >> 6, k = tid & 63;
    int node = (b - 144) * 4 + wid;
    float x = nodes[node];
    hs[wid][k] = fmaxf(x * Wne1[k] + bne1[k], 0.0f);
    __syncthreads();
    float acc = bne2[k];
#pragma unroll 8
    for (int j = 0; j < 64; ++j) acc = fmaf(hs[wid][j], Wne2[j * 64 + k], acc);
    n_bf[(size_t)node * 64 + k] = (bf16_t)acc;
  }
}

// ---------------- CSR build, level 1: coarse 256-bucket scatter + absmax ----------------
// LDS-privatized histogram -> ONE global atomic per (block,bin) (262K total, vs 4.2M
// per-edge device-scope atomics that cost ~99us memory-side in R11's stats kernel).
__global__ __launch_bounds__(256) void coarse_kernel(
    const float* __restrict__ edges_init, const int* __restrict__ recv,
    float* __restrict__ norm, u32* __restrict__ ccur,
    u16* __restrict__ bkt_r, u32* __restrict__ bkt_o) {
  __shared__ u32 hist[256];
  __shared__ u32 base[256];
  __shared__ float mred[4];
  const int tid = threadIdx.x, lane = tid & 63, wid = tid >> 6;
  const int idx = blockIdx.x * 256 + tid;
  hist[tid] = 0;
  __syncthreads();
  int4 r = reinterpret_cast<const int4*>(recv)[idx];
  float4 v = reinterpret_cast<const float4*>(edges_init)[idx];
  float m = fmaxf(fmaxf(fabsf(v.x), fabsf(v.y)), fmaxf(fabsf(v.z), fabsf(v.w)));
#pragma unroll
  for (int off = 32; off > 0; off >>= 1) m = fmaxf(m, __shfl_xor(m, off, 64));
  if (lane == 0) mred[wid] = m;
  atomicAdd(&hist[r.x >> 7], 1u);
  atomicAdd(&hist[r.y >> 7], 1u);
  atomicAdd(&hist[r.z >> 7], 1u);
  atomicAdd(&hist[r.w >> 7], 1u);
  __syncthreads();
  if (tid == 0) {
    float mm = fmaxf(fmaxf(mred[0], mred[1]), fmaxf(mred[2], mred[3]));
    atomicMax(reinterpret_cast<u32*>(norm), __float_as_uint(mm));
  }
  u32 h = hist[tid];
  if (h) base[tid] = atomicAdd(&ccur[tid], h);
  hist[tid] = 0;  // reuse as block-local cursor
  __syncthreads();
  const int e0 = idx * 4;
  int rv4[4] = {r.x, r.y, r.z, r.w};
#pragma unroll
  for (int q = 0; q < 4; ++q) {
    int rv = rv4[q], bk = rv >> 7;
    u32 loc = atomicAdd(&hist[bk], 1u);
    u32 pos = (u32)bk * BCAP + base[bk] + loc;
    bkt_r[pos] = (u16)rv;
    bkt_o[pos] = (u32)(e0 + q);
  }
}

__global__ __launch_bounds__(256) void scan256_kernel(const u32* __restrict__ ccur,
                                                      u32* __restrict__ bbase,
                                                      int* __restrict__ row_ptr) {
  __shared__ u32 s[256];
  const int tid = threadIdx.x;
  s[tid] = ccur[tid];
  __syncthreads();
  if (tid == 0) {
    u32 run = 0;
    for (int j = 0; j < 256; ++j) {
      u32 c = s[j];
      s[j] = run;
      run += c;
    }
    row_ptr[NN] = (int)run;
  }
  __syncthreads();
  bbase[tid] = s[tid];
}

__global__ __launch_bounds__(1024) void bucket_kernel(
    const u32* __restrict__ ccur, const u32* __restrict__ bbase,
    const u16* __restrict__ bkt_r, const u32* __restrict__ bkt_o,
    const int* __restrict__ senders, const float* __restrict__ edges_init,
    int* __restrict__ row_ptr, int* __restrict__ col_idx,
    int* __restrict__ s_perm, int* __restrict__ r_perm, float* __restrict__ x_perm) {
  __shared__ u32 hist[128];
  __shared__ u32 cur[128];
  const int b = blockIdx.x, tid = threadIdx.x;
  const u32 sz = ccur[b], bb = bbase[b];
  if (tid < 128) hist[tid] = 0;
  __syncthreads();
  for (u32 i = tid; i < sz; i += 1024) atomicAdd(&hist[bkt_r[(u32)b * BCAP + i] & 127], 1u);
  __syncthreads();
  if (tid == 0) {
    u32 run = 0;
    for (int j = 0; j < 128; ++j) {
      u32 c = hist[j];
      hist[j] = run;
      cur[j] = run;
      run += c;
    }
  }
  __syncthreads();
  if (tid < 128) row_ptr[b * 128 + tid] = (int)(bb + hist[tid]);
  for (u32 i = tid; i < sz; i += 1024) {
    int rv = (int)bkt_r[(u32)b * BCAP + i];
    int o = (int)bkt_o[(u32)b * BCAP + i];
    u32 loc = atomicAdd(&cur[rv & 127], 1u);
    u32 pos = bb + loc;
    col_idx[pos] = o;
    s_perm[pos] = senders[o];
    r_perm[pos] = rv;
    x_perm[pos] = edges_init[o];
  }
}

// ---------------- mega edge kernel: MODE 0=encode+round0, 1=mid, 2=round4+decode ----------
// R9/R11/R12's proven operating point: NO occupancy clamp (VGPR ~164, 3 waves/SIMD).
// The ~150-reg pipeline state spills catastrophically under any clamp or per-wave work
// increase (R4/R10/R13: 4-6x loss). Phase1 (sequential) 2 groups ahead, phase2 (n-gathers)
// 1 group ahead; all W + loop-invariant constants in LDS; full-line e stores via tr.
template <int MODE>
__global__ __launch_bounds__(256) void edge_update_kernel(
    bf16_t* __restrict__ e, const bf16_t* __restrict__ n_bf,
    const int* __restrict__ col_idx,
    const int* __restrict__ s_perm, const int* __restrict__ r_perm,
    const float* __restrict__ x_perm,
    const bf16_t* __restrict__ wfr,
    const float* __restrict__ beu1, const float* __restrict__ beu2,
    const float* __restrict__ Wee1, const float* __restrict__ bee1,
    const float* __restrict__ bee2, const float* __restrict__ norm_p,
    const float* __restrict__ bd1, const float* __restrict__ Wd2,
    const float* __restrict__ bd2_p, const float* __restrict__ alpha_p,
    float* __restrict__ out) {
  __shared__ alignas(16) bf16_t wstage[40 * 512];  // [W1 0-23][W2 24-31][Wee2|Wd1 32-39]
  __shared__ alignas(16) bf16_t tr[4][16][72];     // per-wave transpose buffer
  __shared__ alignas(16) float fconst[448];        // Wee1|bee1|bee2|bd1|Wd2|beu1|beu2
  const int tid = threadIdx.x, lane = tid & 63, wid = tid >> 6;
  const int l15 = lane & 15, lg = lane >> 4;

#pragma unroll
  for (int j = 0; j < 10; ++j) {
    int c = j * 256 + tid;
    int slot = c >> 6, within = c & 63;
    int sf = (slot < 32) ? slot : (MODE == 2 ? slot + 8 : slot);
    *reinterpret_cast<bf16x8*>(wstage + slot * 512 + within * 8) =
        *reinterpret_cast<const bf16x8*>(wfr + (size_t)sf * 512 + within * 8);
  }
  for (int c = tid; c < 448; c += 256) {
    float v;
    if (c < 64)       v = Wee1[c];
    else if (c < 128) v = bee1[c - 64];
    else if (c < 192) v = bee2[c - 128];
    else if (c < 256) v = bd1[c - 192];
    else if (c < 320) v = Wd2[c - 256];
    else if (c < 384) v = beu1[c - 320];
    else              v = beu2[c - 384];
    fconst[c] = v;
  }
  __syncthreads();  // only block-wide barrier

  float invn = 0.f;
  if constexpr (MODE == 0) invn = 1.0f / *norm_p;
  float nrm = 0.f, alp = 0.f, b2s = 0.f;
  if constexpr (MODE == 2) { nrm = *norm_p; alp = *alpha_p; b2s = *bd2_p; }

  // XCD-aware block swizzle (gridDim.x % 8 == 0)
  const int nb = gridDim.x, cpx = nb >> 3;
  const int bs = (blockIdx.x & 7) * cpx + (blockIdx.x >> 3);
  const int NWAVE = nb * 4;
  const int NG = NE / 16;
  const int g0 = bs * 4 + wid;

  // pipeline state
  int sA, rA, oA, sB, rB, oB, sC, rC, oC;
  float pxA = 0.f, pxB = 0.f, pxC = 0.f;
  bf16x8 eA0, eA1, eB0, eB1, eC0, eC1;
  bf16x8 nA0, nA1, nA2, nA3, nB0, nB1, nB2, nB3;

  auto P1 = [&](int g, int& s, int& r, int& o, float& px, bf16x8& e0, bf16x8& e1) {
    int row = g * 16 + l15;
    s = s_perm[row];
    r = r_perm[row];
    if constexpr (MODE != 1) px = x_perm[row];
    if constexpr (MODE == 2) o = col_idx[row];
    if constexpr (MODE != 0) {
      const bf16x8* er = reinterpret_cast<const bf16x8*>(e + (size_t)row * 64);
      e0 = er[lg];
      e1 = er[4 + lg];
    }
  };
  auto P2 = [&](int s, int r, bf16x8& n0, bf16x8& n1, bf16x8& n2, bf16x8& n3) {
    const bf16x8* sp = reinterpret_cast<const bf16x8*>(n_bf + (size_t)s * 64);
    n0 = sp[lg];
    n1 = sp[4 + lg];
    const bf16x8* rp = reinterpret_cast<const bf16x8*>(n_bf + (size_t)r * 64);
    n2 = rp[lg];
    n3 = rp[4 + lg];
  };

  if (g0 < NG) {
    P1(g0, sA, rA, oA, pxA, eA0, eA1);
    P2(sA, rA, nA0, nA1, nA2, nA3);
    int g1 = g0 + NWAVE;
    if (g1 < NG) P1(g1, sB, rB, oB, pxB, eB0, eB1);
  }

  for (int g = g0; g < NG; g += NWAVE) {
    const int gB = g + NWAVE, gC = g + 2 * NWAVE;
    if (gB < NG) P2(sB, rB, nB0, nB1, nB2, nB3);
    if (gC < NG) P1(gC, sC, rC, oC, pxC, eC0, eC1);

    // === compute on group g ===
    bf16x8 ce0, ce1;
    if constexpr (MODE == 0) {
      float xv = pxA * invn;
      f32x4 wl0 = *reinterpret_cast<const f32x4*>(&fconst[lg * 8]);
      f32x4 wl1 = *reinterpret_cast<const f32x4*>(&fconst[lg * 8 + 4]);
      f32x4 wh0 = *reinterpret_cast<const f32x4*>(&fconst[32 + lg * 8]);
      f32x4 wh1 = *reinterpret_cast<const f32x4*>(&fconst[32 + lg * 8 + 4]);
      f32x4 bl0 = *reinterpret_cast<const f32x4*>(&fconst[64 + lg * 8]);
      f32x4 bl1 = *reinterpret_cast<const f32x4*>(&fconst[64 + lg * 8 + 4]);
      f32x4 bh0 = *reinterpret_cast<const f32x4*>(&fconst[96 + lg * 8]);
      f32x4 bh1 = *reinterpret_cast<const f32x4*>(&fconst[96 + lg * 8 + 4]);
      bf16x8 h0, h1;
#pragma unroll
      for (int i = 0; i < 4; ++i) {
        h0[i]     = (bf16_t)fmaxf(fmaf(xv, wl0[i], bl0[i]), 0.0f);
        h0[4 + i] = (bf16_t)fmaxf(fmaf(xv, wl1[i], bl1[i]), 0.0f);
        h1[i]     = (bf16_t)fmaxf(fmaf(xv, wh0[i], bh0[i]), 0.0f);
        h1[4 + i] = (bf16_t)fmaxf(fmaf(xv, wh1[i], bh1[i]), 0.0f);
      }
      f32x4 ae[4];
#pragma unroll
      for (int nt = 0; nt < 4; ++nt)
        ae[nt] = *reinterpret_cast<const f32x4*>(&fconst[128 + nt * 16 + lg * 4]);
#pragma unroll
      for (int kt = 0; kt < 2; ++kt)
#pragma unroll
        for (int nt = 0; nt < 4; ++nt) {
          bf16x8 wf = *reinterpret_cast<const bf16x8*>(wstage + (32 + kt * 4 + nt) * 512 + lane * 8);
          ae[nt] = __builtin_amdgcn_mfma_f32_16x16x32_bf16(wf, kt ? h1 : h0, ae[nt], 0, 0, 0);
        }
#pragma unroll
      for (int nt = 0; nt < 4; ++nt) {
        bf16x4 pk;
#pragma unroll
        for (int r = 0; r < 4; ++r) pk[r] = (bf16_t)ae[nt][r];
        *reinterpret_cast<bf16x4*>(&tr[wid][l15][nt * 16 + lg * 4]) = pk;
      }
      ce0 = *reinterpret_cast<const bf16x8*>(&tr[wid][l15][lg * 8]);
      ce1 = *reinterpret_cast<const bf16x8*>(&tr[wid][l15][32 + lg * 8]);
    } else {
      ce0 = eA0;
      ce1 = eA1;
    }

    // layer 1
    f32x4 acc[4];
#pragma unroll
    for (int nt = 0; nt < 4; ++nt)
      acc[nt] = *reinterpret_cast<const f32x4*>(&fconst[320 + nt * 16 + lg * 4]);
#pragma unroll
    for (int kt = 0; kt < 6; ++kt) {
      bf16x8 m = (kt == 0) ? ce0 : (kt == 1) ? ce1 : (kt == 2) ? nA0
               : (kt == 3) ? nA1 : (kt == 4) ? nA2 : nA3;
#pragma unroll
      for (int nt = 0; nt < 4; ++nt) {
        bf16x8 w = *reinterpret_cast<const bf16x8*>(wstage + (kt * 4 + nt) * 512 + lane * 8);
        acc[nt] = __builtin_amdgcn_mfma_f32_16x16x32_bf16(w, m, acc[nt], 0, 0, 0);
      }
    }

    // relu -> transpose to B-frag
#pragma unroll
    for (int nt = 0; nt < 4; ++nt) {
      bf16x4 pk;
#pragma unroll
      for (int r = 0; r < 4; ++r) pk[r] = (bf16_t)fmaxf(acc[nt][r], 0.0f);
      *reinterpret_cast<bf16x4*>(&tr[wid][l15][nt * 16 + lg * 4]) = pk;
    }
    bf16x8 hh0 = *reinterpret_cast<const bf16x8*>(&tr[wid][l15][lg * 8]);
    bf16x8 hh1 = *reinterpret_cast<const bf16x8*>(&tr[wid][l15][32 + lg * 8]);

    // layer 2
    f32x4 acc2[4];
#pragma unroll
    for (int nt = 0; nt < 4; ++nt)
      acc2[nt] = *reinterpret_cast<const f32x4*>(&fconst[384 + nt * 16 + lg * 4]);
#pragma unroll
    for (int kt = 0; kt < 2; ++kt)
#pragma unroll
      for (int nt = 0; nt < 4; ++nt) {
        bf16x8 w = *reinterpret_cast<const bf16x8*>(wstage + (24 + kt * 4 + nt) * 512 + lane * 8);
        acc2[nt] = __builtin_amdgcn_mfma_f32_16x16x32_bf16(w, kt ? hh1 : hh0, acc2[nt], 0, 0, 0);
      }

    if constexpr (MODE == 2) {
      // decoder fused; final e never stored
#pragma unroll
      for (int nt = 0; nt < 4; ++nt) {
        bf16x4 pk;
#pragma unroll
        for (int r = 0; r < 4; ++r) pk[r] = (bf16_t)acc2[nt][r];
        *reinterpret_cast<bf16x4*>(&tr[wid][l15][nt * 16 + lg * 4]) = pk;
      }
      bf16x8 eb0 = *reinterpret_cast<const bf16x8*>(&tr[wid][l15][lg * 8]);
      bf16x8 eb1 = *reinterpret_cast<const bf16x8*>(&tr[wid][l15][32 + lg * 8]);
      f32x4 ad[4];
#pragma unroll
      for (int nt = 0; nt < 4; ++nt)
        ad[nt] = *reinterpret_cast<const f32x4*>(&fconst[192 + nt * 16 + lg * 4]);
#pragma unroll
      for (int kt = 0; kt < 2; ++kt)
#pragma unroll
        for (int nt = 0; nt < 4; ++nt) {
          bf16x8 wf = *reinterpret_cast<const bf16x8*>(wstage + (32 + kt * 4 + nt) * 512 + lane * 8);
          ad[nt] = __builtin_amdgcn_mfma_f32_16x16x32_bf16(wf, kt ? eb1 : eb0, ad[nt], 0, 0, 0);
        }
      float s = 0.0f;
#pragma unroll
      for (int nt = 0; nt < 4; ++nt) {
        f32x4 w2 = *reinterpret_cast<const f32x4*>(&fconst[256 + nt * 16 + lg * 4]);
#pragma unroll
        for (int r = 0; r < 4; ++r) s = fmaf(fmaxf(ad[nt][r], 0.0f), w2[r], s);
      }
      s += __shfl_xor(s, 16, 64);
      s += __shfl_xor(s, 32, 64);
      if (lg == 0) {
        float dv = s + b2s;
        out[oA] = (rA >= sA) ? fmaf(alp * nrm, dv, pxA) : 0.0f;
      }
    } else {
      // full-line store: acc2 -> tr -> 2x contiguous 1KB stores (16B/lane)
#pragma unroll
      for (int nt = 0; nt < 4; ++nt) {
        bf16x4 pk;
#pragma unroll
        for (int r = 0; r < 4; ++r) pk[r] = (bf16_t)acc2[nt][r];
        *reinterpret_cast<bf16x4*>(&tr[wid][l15][nt * 16 + lg * 4]) = pk;
      }
      const int rr = lane >> 3, cc = lane & 7;
      bf16x8 w0 = *reinterpret_cast<const bf16x8*>(&tr[wid][rr][cc * 8]);
      bf16x8 w1 = *reinterpret_cast<const bf16x8*>(&tr[wid][8 + rr][cc * 8]);
      *reinterpret_cast<bf16x8*>(e + (size_t)(g * 16 + rr) * 64 + cc * 8) = w0;
      *reinterpret_cast<bf16x8*>(e + (size_t)(g * 16 + 8 + rr) * 64 + cc * 8) = w1;
    }

    // rotate pipeline state
    sA = sB; rA = rB; oA = oB; pxA = pxB;
    eA0 = eB0; eA1 = eB1;
    nA0 = nB0; nA1 = nB1; nA2 = nB2; nA3 = nB3;
    sB = sC; rB = rC; oB = oC; pxB = pxC;
    eB0 = eC0; eB1 = eC1;
  }
}

// ---------------- agg: full-occupancy streaming segment-sum ----------------
__global__ __launch_bounds__(256) void agg_kernel(const bf16_t* __restrict__ e,
                                                  const int* __restrict__ row_ptr,
                                                  bf16_t* __restrict__ agg) {
  const int lane = threadIdx.x & 63, wid = threadIdx.x >> 6;
  const int rsub = lane >> 3;
  const int gw = blockIdx.x * 4 + wid, NWV = gridDim.x * 4;
  for (int node = gw; node < NN; node += NWV) {
    const int p0 = row_ptr[node], cnt = row_ptr[node + 1] - p0;
    float a[8] = {0, 0, 0, 0, 0, 0, 0, 0};
    const bf16x8* bb = reinterpret_cast<const bf16x8*>(e + (size_t)p0 * 64) + lane;
    const int nchunk = (cnt + 7) >> 3;
    int c = 0;
    for (; c + 4 <= nchunk; c += 4) {
      bf16x8 v0 = bb[(size_t)(c + 0) * 64];
      bf16x8 v1 = bb[(size_t)(c + 1) * 64];
      bf16x8 v2 = bb[(size_t)(c + 2) * 64];
      bf16x8 v3 = bb[(size_t)(c + 3) * 64];
      {
#pragma unroll
        for (int i = 0; i < 8; ++i) a[i] += (float)v0[i];
#pragma unroll
        for (int i = 0; i < 8; ++i) a[i] += (float)v1[i];
#pragma unroll
        for (int i = 0; i < 8; ++i) a[i] += (float)v2[i];
      }
      if ((c + 3) * 8 + rsub < cnt) {
#pragma unroll
        for (int i = 0; i < 8; ++i) a[i] += (float)v3[i];
      }
    }
    for (; c < nchunk; ++c) {
      bf16x8 v = bb[(size_t)c * 64];
      if (c * 8 + rsub < cnt) {
#pragma unroll
        for (int i = 0; i < 8; ++i) a[i] += (float)v[i];
      }
    }
#pragma unroll
    for (int i = 0; i < 8; ++i) {
      a[i] += __shfl_xor(a[i], 8, 64);
      a[i] += __shfl_xor(a[i], 16, 64);
      a[i] += __shfl_xor(a[i], 32, 64);
    }
    if (lane < 8) {
      bf16x8 pk;
#pragma unroll
      for (int i = 0; i < 8; ++i) pk[i] = (bf16_t)a[i];
      *reinterpret_cast<bf16x8*>(agg + (size_t)node * 64 + lane * 8) = pk;
    }
  }
}

// ---------------- node MLP via MFMA (16 nodes per wave-task) ----------------
__global__ __launch_bounds__(256) void node_mlp_kernel(
    const bf16_t* __restrict__ agg, const bf16_t* __restrict__ wfr,
    const float* __restrict__ bnu1, const float* __restrict__ bnu2,
    bf16_t* __restrict__ n_bf) {
  __shared__ alignas(16) bf16_t w2s[8 * 512];   // Wnu2 frags (64-71), 8 KB
  __shared__ alignas(16) bf16_t xb[4][16][72];  // per-wave transpose buffer
  const int tid = threadIdx.x, lane = tid & 63, wid = tid >> 6;
  const int l15 = lane & 15, lg = lane >> 4;

  bf16x8 W1r[16];  // Wnu1 frags 48-63 (K=128 -> kt<4, nt<4)
#pragma unroll
  for (int f = 0; f < 16; ++f)
    W1r[f] = *reinterpret_cast<const bf16x8*>(wfr + (size_t)(48 + f) * 512 + lane * 8);
#pragma unroll
  for (int j = 0; j < 2; ++j)
    reinterpret_cast<bf16x8*>(w2s)[j * 256 + tid] =
        reinterpret_cast<const bf16x8*>(wfr + (size_t)64 * 512)[j * 256 + tid];
  __syncthreads();

  f32x4 b1q[4], b2q[4];
#pragma unroll
  for (int nt = 0; nt < 4; ++nt) {
    b1q[nt] = *reinterpret_cast<const f32x4*>(bnu1 + nt * 16 + lg * 4);
    b2q[nt] = *reinterpret_cast<const f32x4*>(bnu2 + nt * 16 + lg * 4);
  }

  const int NT = NN / 16;
  for (int task = blockIdx.x * 4 + wid; task < NT; task += gridDim.x * 4) {
    const int base = task * 16;
    bf16x8 xn0 = *reinterpret_cast<const bf16x8*>(n_bf + (size_t)(base + l15) * 64 + lg * 8);
    bf16x8 xn1 = *reinterpret_cast<const bf16x8*>(n_bf + (size_t)(base + l15) * 64 + 32 + lg * 8);
    bf16x8 xa0 = *reinterpret_cast<const bf16x8*>(agg + (size_t)(base + l15) * 64 + lg * 8);
    bf16x8 xa1 = *reinterpret_cast<const bf16x8*>(agg + (size_t)(base + l15) * 64 + 32 + lg * 8);
    f32x4 acc[4];
#pragma unroll
    for (int nt = 0; nt < 4; ++nt) acc[nt] = b1q[nt];
#pragma unroll
    for (int kt = 0; kt < 4; ++kt) {
      bf16x8 x = (kt == 0) ? xn0 : (kt == 1) ? xn1 : (kt == 2) ? xa0 : xa1;
#pragma unroll
      for (int nt = 0; nt < 4; ++nt)
        acc[nt] = __builtin_amdgcn_mfma_f32_16x16x32_bf16(W1r[kt * 4 + nt], x, acc[nt], 0, 0, 0);
    }
#pragma unroll
    for (int nt = 0; nt < 4; ++nt) {
      bf16x4 pk;
#pragma unroll
      for (int r = 0; r < 4; ++r) pk[r] = (bf16_t)fmaxf(acc[nt][r], 0.0f);
      *reinterpret_cast<bf16x4*>(&xb[wid][l15][nt * 16 + lg * 4]) = pk;
    }
    bf16x8 hh0 = *reinterpret_cast<const bf16x8*>(&xb[wid][l15][lg * 8]);
    bf16x8 hh1 = *reinterpret_cast<const bf16x8*>(&xb[wid][l15][32 + lg * 8]);
    f32x4 acc2[4];
#pragma unroll
    for (int nt = 0; nt < 4; ++nt) acc2[nt] = b2q[nt];
#pragma unroll
    for (int kt = 0; kt < 2; ++kt)
#pragma unroll
      for (int nt = 0; nt < 4; ++nt) {
        bf16x8 w = *reinterpret_cast<const bf16x8*>(w2s + (kt * 4 + nt) * 512 + lane * 8);
        acc2[nt] = __builtin_amdgcn_mfma_f32_16x16x32_bf16(w, kt ? hh1 : hh0, acc2[nt], 0, 0, 0);
      }
#pragma unroll
    for (int nt = 0; nt < 4; ++nt) {
      bf16x4 pk;
#pragma unroll
      for (int r = 0; r < 4; ++r) pk[r] = (bf16_t)acc2[nt][r];
      *reinterpret_cast<bf16x4*>(n_bf + (size_t)(base + l15) * 64 + nt * 16 + lg * 4) = pk;
    }
  }
}

extern "C" void kernel_launch(void* const* d_in, const int* in_sizes, int n_in,
                              void* d_out, int out_size, void* d_ws, size_t ws_size,
                              hipStream_t stream) {
  const float* nodes      = (const float*)d_in[0];
  const float* edges_init = (const float*)d_in[1];
  const int*   receivers  = (const int*)d_in[2];
  const int*   senders    = (const int*)d_in[3];
  const float* Wne1 = (const float*)d_in[4];
  const float* bne1 = (const float*)d_in[5];
  const float* Wne2 = (const float*)d_in[6];
  const float* bne2 = (const float*)d_in[7];
  const float* Wee1 = (const float*)d_in[8];
  const float* bee1 = (const float*)d_in[9];
  const float* Wee2 = (const float*)d_in[10];
  const float* bee2 = (const float*)d_in[11];
  const float* Weu1 = (const float*)d_in[12];
  const float* beu1 = (const float*)d_in[13];
  const float* Weu2 = (const float*)d_in[14];
  const float* beu2 = (const float*)d_in[15];
  const float* Wnu1 = (const float*)d_in[16];
  const float* bnu1 = (const float*)d_in[17];
  const float* Wnu2 = (const float*)d_in[18];
  const float* bnu2 = (const float*)d_in[19];
  const float* Wd1  = (const float*)d_in[20];
  const float* bd1  = (const float*)d_in[21];
  const float* Wd2  = (const float*)d_in[22];
  const float* bd2  = (const float*)d_in[23];
  const float* alpha = (const float*)d_in[24];
  float* out = (float*)d_out;
  (void)in_sizes; (void)n_in; (void)out_size; (void)ws_size;

  char* ws = (char*)d_ws;
  size_t off = 0;
  auto alloc = [&](size_t bytes) -> void* {
    void* p = ws + off;
    off = (off + bytes + 255) & ~(size_t)255;
    return p;
  };
  float*  norm    = (float*)alloc(4);
  u32*    ccur    = (u32*)alloc(sizeof(u32) * 256);
  u32*    bbase   = (u32*)alloc(sizeof(u32) * 256);
  int*    row_ptr = (int*)alloc(sizeof(int) * (NN + 1));
  u16*    bkt_r   = (u16*)alloc(sizeof(u16) * 256 * BCAP);
  u32*    bkt_o   = (u32*)alloc(sizeof(u32) * 256 * BCAP);
  int*    col_idx = (int*)alloc(sizeof(int) * NE);
  int*    s_perm  = (int*)alloc(sizeof(int) * NE);
  int*    r_perm  = (int*)alloc(sizeof(int) * NE);
  float*  x_perm  = (float*)alloc(sizeof(float) * NE);
  bf16_t* n_bf    = (bf16_t*)alloc(sizeof(bf16_t) * (size_t)NN * 64);
  bf16_t* agg     = (bf16_t*)alloc(sizeof(bf16_t) * (size_t)NN * 64);
  bf16_t* e_buf   = (bf16_t*)alloc(sizeof(bf16_t) * (size_t)NE * 64 + 4096);  // +pad: agg tail overread
  bf16_t* wfr     = (bf16_t*)alloc(sizeof(bf16_t) * 72 * 512);

  hipMemsetAsync(norm, 0, 4, stream);
  hipMemsetAsync(ccur, 0, sizeof(u32) * 256, stream);

  prep_encode_kernel<<<8336, 256, 0, stream>>>(Weu1, Weu2, Wee2, Wd1, Wnu1, Wnu2, wfr,
                                               nodes, Wne1, bne1, Wne2, bne2, n_bf);
  coarse_kernel<<<1024, 256, 0, stream>>>(edges_init, receivers, norm, ccur, bkt_r, bkt_o);
  scan256_kernel<<<1, 256, 0, stream>>>(ccur, bbase, row_ptr);
  bucket_kernel<<<256, 1024, 0, stream>>>(ccur, bbase, bkt_r, bkt_o, senders, edges_init,
                                          row_ptr, col_idx, s_perm, r_perm, x_perm);

  edge_update_kernel<0><<<768, 256, 0, stream>>>(
      e_buf, n_bf, col_idx, s_perm, r_perm, x_perm, wfr, beu1, beu2,
      Wee1, bee1, bee2, norm, bd1, Wd2, bd2, alpha, out);
  for (int t = 1; t <= 4; ++t) {
    agg_kernel<<<2048, 256, 0, stream>>>(e_buf, row_ptr, agg);
    node_mlp_kernel<<<512, 256, 0, stream>>>(agg, wfr, bnu1, bnu2, n_bf);
    if (t < 4)
      edge_update_kernel<1><<<768, 256, 0, stream>>>(
          e_buf, n_bf, col_idx, s_perm, r_perm, x_perm, wfr, beu1, beu2,
          Wee1, bee1, bee2, norm, bd1, Wd2, bd2, alpha, out);
    else
      edge_update_kernel<2><<<768, 256, 0, stream>>>(
          e_buf, n_bf, col_idx, s_perm, r_perm, x_perm, wfr, beu1, beu2,
          Wee1, bee1, bee2, norm, bd1, Wd2, bd2, alpha, out);
  }
}

// Round 15
// 538.790 us; speedup vs baseline: 3.0511x; 1.1250x over previous
//
#include <hip/hip_runtime.h>

#define NN 32768
#define NE 1048576
#define BCAP 5120  // per-bucket capacity; mean 4096, sigma 64 -> 16 sigma headroom

typedef __bf16 bf16_t;
typedef __bf16 bf16x8 __attribute__((ext_vector_type(8)));
typedef __bf16 bf16x4 __attribute__((ext_vector_type(4)));
typedef float f32x4 __attribute__((ext_vector_type(4)));
typedef unsigned int u32;
typedef unsigned short u16;

// ---------------- prologue: weight-frag prep | node encoder ----------------
// wfr layout (72 frags x 512), all 16x16 frags (lane: dim=nt*16+(l&15), k=kt*32+(l>>4)*8+i):
//   0-23 Weu1 | 24-31 Weu2 | 32-39 Wee2 | 40-47 Wd1 | 48-63 Wnu1 (K=128) | 64-71 Wnu2
__global__ __launch_bounds__(256) void prep_encode_kernel(
    const float* __restrict__ Weu1, const float* __restrict__ Weu2,
    const float* __restrict__ Wee2, const float* __restrict__ Wd1,
    const float* __restrict__ Wnu1, const float* __restrict__ Wnu2,
    bf16_t* __restrict__ wfr,
    const float* __restrict__ nodes, const float* __restrict__ Wne1,
    const float* __restrict__ bne1, const float* __restrict__ Wne2,
    const float* __restrict__ bne2, bf16_t* __restrict__ n_bf) {
  const int b = blockIdx.x, tid = threadIdx.x;
  if (b < 144) {
    int idx = b * 256 + tid;  // < 36864 = 72 frags
    int i = idx & 7, lane = (idx >> 3) & 63, f = idx >> 9;
    const float* W;
    int fl;
    if (f < 24)      { W = Weu1; fl = f; }
    else if (f < 32) { W = Weu2; fl = f - 24; }
    else if (f < 40) { W = Wee2; fl = f - 32; }
    else if (f < 48) { W = Wd1;  fl = f - 40; }
    else if (f < 64) { W = Wnu1; fl = f - 48; }
    else             { W = Wnu2; fl = f - 64; }
    int kt = fl >> 2, nt = fl & 3;
    int k = kt * 32 + ((lane >> 4) << 3) + i;
    int col = nt * 16 + (lane & 15);
    wfr[idx] = (bf16_t)W[k * 64 + col];
  } else {
    __shared__ float hs[4][64];
    int wid = tid >> 6, k = tid & 63;
    int node = (b - 144) * 4 + wid;
    float x = nodes[node];
    hs[wid][k] = fmaxf(x * Wne1[k] + bne1[k], 0.0f);
    __syncthreads();
    float acc = bne2[k];
#pragma unroll 8
    for (int j = 0; j < 64; ++j) acc = fmaf(hs[wid][j], Wne2[j * 64 + k], acc);
    n_bf[(size_t)node * 64 + k] = (bf16_t)acc;
  }
}

// ---------------- CSR build, level 1: coarse 256-bucket scatter + absmax ----------------
__global__ __launch_bounds__(256) void coarse_kernel(
    const float* __restrict__ edges_init, const int* __restrict__ recv,
    float* __restrict__ norm, u32* __restrict__ ccur,
    u16* __restrict__ bkt_r, u32* __restrict__ bkt_o) {
  __shared__ u32 hist[256];
  __shared__ u32 base[256];
  __shared__ float mred[4];
  const int tid = threadIdx.x, lane = tid & 63, wid = tid >> 6;
  const int idx = blockIdx.x * 256 + tid;
  hist[tid] = 0;
  __syncthreads();
  int4 r = reinterpret_cast<const int4*>(recv)[idx];
  float4 v = reinterpret_cast<const float4*>(edges_init)[idx];
  float m = fmaxf(fmaxf(fabsf(v.x), fabsf(v.y)), fmaxf(fabsf(v.z), fabsf(v.w)));
#pragma unroll
  for (int off = 32; off > 0; off >>= 1) m = fmaxf(m, __shfl_xor(m, off, 64));
  if (lane == 0) mred[wid] = m;
  atomicAdd(&hist[r.x >> 7], 1u);
  atomicAdd(&hist[r.y >> 7], 1u);
  atomicAdd(&hist[r.z >> 7], 1u);
  atomicAdd(&hist[r.w >> 7], 1u);
  __syncthreads();
  if (tid == 0) {
    float mm = fmaxf(fmaxf(mred[0], mred[1]), fmaxf(mred[2], mred[3]));
    atomicMax(reinterpret_cast<u32*>(norm), __float_as_uint(mm));
  }
  u32 h = hist[tid];
  if (h) base[tid] = atomicAdd(&ccur[tid], h);
  hist[tid] = 0;  // reuse as block-local cursor
  __syncthreads();
  const int e0 = idx * 4;
  int rv4[4] = {r.x, r.y, r.z, r.w};
#pragma unroll
  for (int q = 0; q < 4; ++q) {
    int rv = rv4[q], bk = rv >> 7;
    u32 loc = atomicAdd(&hist[bk], 1u);
    u32 pos = (u32)bk * BCAP + base[bk] + loc;
    bkt_r[pos] = (u16)rv;
    bkt_o[pos] = (u32)(e0 + q);
  }
}

__global__ __launch_bounds__(256) void scan256_kernel(const u32* __restrict__ ccur,
                                                      u32* __restrict__ bbase,
                                                      int* __restrict__ row_ptr) {
  __shared__ u32 s[256];
  const int tid = threadIdx.x;
  s[tid] = ccur[tid];
  __syncthreads();
  if (tid == 0) {
    u32 run = 0;
    for (int j = 0; j < 256; ++j) {
      u32 c = s[j];
      s[j] = run;
      run += c;
    }
    row_ptr[NN] = (int)run;
  }
  __syncthreads();
  bbase[tid] = s[tid];
}

__global__ __launch_bounds__(1024) void bucket_kernel(
    const u32* __restrict__ ccur, const u32* __restrict__ bbase,
    const u16* __restrict__ bkt_r, const u32* __restrict__ bkt_o,
    const int* __restrict__ senders, const float* __restrict__ edges_init,
    int* __restrict__ row_ptr, int* __restrict__ col_idx,
    int* __restrict__ s_perm, int* __restrict__ r_perm, float* __restrict__ x_perm) {
  __shared__ u32 hist[128];
  __shared__ u32 cur[128];
  const int b = blockIdx.x, tid = threadIdx.x;
  const u32 sz = ccur[b], bb = bbase[b];
  if (tid < 128) hist[tid] = 0;
  __syncthreads();
  for (u32 i = tid; i < sz; i += 1024) atomicAdd(&hist[bkt_r[(u32)b * BCAP + i] & 127], 1u);
  __syncthreads();
  if (tid == 0) {
    u32 run = 0;
    for (int j = 0; j < 128; ++j) {
      u32 c = hist[j];
      hist[j] = run;
      cur[j] = run;
      run += c;
    }
  }
  __syncthreads();
  if (tid < 128) row_ptr[b * 128 + tid] = (int)(bb + hist[tid]);
  for (u32 i = tid; i < sz; i += 1024) {
    int rv = (int)bkt_r[(u32)b * BCAP + i];
    int o = (int)bkt_o[(u32)b * BCAP + i];
    u32 loc = atomicAdd(&cur[rv & 127], 1u);
    u32 pos = bb + loc;
    col_idx[pos] = o;
    s_perm[pos] = senders[o];
    r_perm[pos] = rv;
    x_perm[pos] = edges_init[o];
  }
}

// ---------------- mega edge kernel: MODE 0=encode+round0, 1=mid, 2=round4+decode ----------
// R9/R11/R12/R14's proven operating point: NO occupancy clamp (VGPR ~164, 3 waves/SIMD).
// The ~150-reg pipeline state spills catastrophically under any clamp or per-wave work
// increase (R4/R10/R13: 4-6x loss). s_setprio(1) wraps MFMA clusters (waves are
// barrier-free/desynced -> scheduler can favor the MFMA-issuing wave).
template <int MODE>
__global__ __launch_bounds__(256) void edge_update_kernel(
    bf16_t* __restrict__ e, const bf16_t* __restrict__ n_bf,
    const int* __restrict__ col_idx,
    const int* __restrict__ s_perm, const int* __restrict__ r_perm,
    const float* __restrict__ x_perm,
    const bf16_t* __restrict__ wfr,
    const float* __restrict__ beu1, const float* __restrict__ beu2,
    const float* __restrict__ Wee1, const float* __restrict__ bee1,
    const float* __restrict__ bee2, const float* __restrict__ norm_p,
    const float* __restrict__ bd1, const float* __restrict__ Wd2,
    const float* __restrict__ bd2_p, const float* __restrict__ alpha_p,
    float* __restrict__ out) {
  __shared__ alignas(16) bf16_t wstage[40 * 512];  // [W1 0-23][W2 24-31][Wee2|Wd1 32-39]
  __shared__ alignas(16) bf16_t tr[4][16][72];     // per-wave transpose buffer
  __shared__ alignas(16) float fconst[448];        // Wee1|bee1|bee2|bd1|Wd2|beu1|beu2
  const int tid = threadIdx.x, lane = tid & 63, wid = tid >> 6;
  const int l15 = lane & 15, lg = lane >> 4;

#pragma unroll
  for (int j = 0; j < 10; ++j) {
    int c = j * 256 + tid;
    int slot = c >> 6, within = c & 63;
    int sf = (slot < 32) ? slot : (MODE == 2 ? slot + 8 : slot);
    *reinterpret_cast<bf16x8*>(wstage + slot * 512 + within * 8) =
        *reinterpret_cast<const bf16x8*>(wfr + (size_t)sf * 512 + within * 8);
  }
  for (int c = tid; c < 448; c += 256) {
    float v;
    if (c < 64)       v = Wee1[c];
    else if (c < 128) v = bee1[c - 64];
    else if (c < 192) v = bee2[c - 128];
    else if (c < 256) v = bd1[c - 192];
    else if (c < 320) v = Wd2[c - 256];
    else if (c < 384) v = beu1[c - 320];
    else              v = beu2[c - 384];
    fconst[c] = v;
  }
  __syncthreads();  // only block-wide barrier

  float invn = 0.f;
  if constexpr (MODE == 0) invn = 1.0f / *norm_p;
  float nrm = 0.f, alp = 0.f, b2s = 0.f;
  if constexpr (MODE == 2) { nrm = *norm_p; alp = *alpha_p; b2s = *bd2_p; }

  // XCD-aware block swizzle (gridDim.x % 8 == 0)
  const int nb = gridDim.x, cpx = nb >> 3;
  const int bs = (blockIdx.x & 7) * cpx + (blockIdx.x >> 3);
  const int NWAVE = nb * 4;
  const int NG = NE / 16;
  const int g0 = bs * 4 + wid;

  // pipeline state
  int sA, rA, oA, sB, rB, oB, sC, rC, oC;
  float pxA = 0.f, pxB = 0.f, pxC = 0.f;
  bf16x8 eA0, eA1, eB0, eB1, eC0, eC1;
  bf16x8 nA0, nA1, nA2, nA3, nB0, nB1, nB2, nB3;

  auto P1 = [&](int g, int& s, int& r, int& o, float& px, bf16x8& e0, bf16x8& e1) {
    int row = g * 16 + l15;
    s = s_perm[row];
    r = r_perm[row];
    if constexpr (MODE != 1) px = x_perm[row];
    if constexpr (MODE == 2) o = col_idx[row];
    if constexpr (MODE != 0) {
      const bf16x8* er = reinterpret_cast<const bf16x8*>(e + (size_t)row * 64);
      e0 = er[lg];
      e1 = er[4 + lg];
    }
  };
  auto P2 = [&](int s, int r, bf16x8& n0, bf16x8& n1, bf16x8& n2, bf16x8& n3) {
    const bf16x8* sp = reinterpret_cast<const bf16x8*>(n_bf + (size_t)s * 64);
    n0 = sp[lg];
    n1 = sp[4 + lg];
    const bf16x8* rp = reinterpret_cast<const bf16x8*>(n_bf + (size_t)r * 64);
    n2 = rp[lg];
    n3 = rp[4 + lg];
  };

  if (g0 < NG) {
    P1(g0, sA, rA, oA, pxA, eA0, eA1);
    P2(sA, rA, nA0, nA1, nA2, nA3);
    int g1 = g0 + NWAVE;
    if (g1 < NG) P1(g1, sB, rB, oB, pxB, eB0, eB1);
  }

  for (int g = g0; g < NG; g += NWAVE) {
    const int gB = g + NWAVE, gC = g + 2 * NWAVE;
    if (gB < NG) P2(sB, rB, nB0, nB1, nB2, nB3);
    if (gC < NG) P1(gC, sC, rC, oC, pxC, eC0, eC1);

    // === compute on group g ===
    bf16x8 ce0, ce1;
    if constexpr (MODE == 0) {
      float xv = pxA * invn;
      f32x4 wl0 = *reinterpret_cast<const f32x4*>(&fconst[lg * 8]);
      f32x4 wl1 = *reinterpret_cast<const f32x4*>(&fconst[lg * 8 + 4]);
      f32x4 wh0 = *reinterpret_cast<const f32x4*>(&fconst[32 + lg * 8]);
      f32x4 wh1 = *reinterpret_cast<const f32x4*>(&fconst[32 + lg * 8 + 4]);
      f32x4 bl0 = *reinterpret_cast<const f32x4*>(&fconst[64 + lg * 8]);
      f32x4 bl1 = *reinterpret_cast<const f32x4*>(&fconst[64 + lg * 8 + 4]);
      f32x4 bh0 = *reinterpret_cast<const f32x4*>(&fconst[96 + lg * 8]);
      f32x4 bh1 = *reinterpret_cast<const f32x4*>(&fconst[96 + lg * 8 + 4]);
      bf16x8 h0, h1;
#pragma unroll
      for (int i = 0; i < 4; ++i) {
        h0[i]     = (bf16_t)fmaxf(fmaf(xv, wl0[i], bl0[i]), 0.0f);
        h0[4 + i] = (bf16_t)fmaxf(fmaf(xv, wl1[i], bl1[i]), 0.0f);
        h1[i]     = (bf16_t)fmaxf(fmaf(xv, wh0[i], bh0[i]), 0.0f);
        h1[4 + i] = (bf16_t)fmaxf(fmaf(xv, wh1[i], bh1[i]), 0.0f);
      }
      f32x4 ae[4];
#pragma unroll
      for (int nt = 0; nt < 4; ++nt)
        ae[nt] = *reinterpret_cast<const f32x4*>(&fconst[128 + nt * 16 + lg * 4]);
      __builtin_amdgcn_s_setprio(1);
#pragma unroll
      for (int kt = 0; kt < 2; ++kt)
#pragma unroll
        for (int nt = 0; nt < 4; ++nt) {
          bf16x8 wf = *reinterpret_cast<const bf16x8*>(wstage + (32 + kt * 4 + nt) * 512 + lane * 8);
          ae[nt] = __builtin_amdgcn_mfma_f32_16x16x32_bf16(wf, kt ? h1 : h0, ae[nt], 0, 0, 0);
        }
      __builtin_amdgcn_s_setprio(0);
#pragma unroll
      for (int nt = 0; nt < 4; ++nt) {
        bf16x4 pk;
#pragma unroll
        for (int r = 0; r < 4; ++r) pk[r] = (bf16_t)ae[nt][r];
        *reinterpret_cast<bf16x4*>(&tr[wid][l15][nt * 16 + lg * 4]) = pk;
      }
      ce0 = *reinterpret_cast<const bf16x8*>(&tr[wid][l15][lg * 8]);
      ce1 = *reinterpret_cast<const bf16x8*>(&tr[wid][l15][32 + lg * 8]);
    } else {
      ce0 = eA0;
      ce1 = eA1;
    }

    // layer 1
    f32x4 acc[4];
#pragma unroll
    for (int nt = 0; nt < 4; ++nt)
      acc[nt] = *reinterpret_cast<const f32x4*>(&fconst[320 + nt * 16 + lg * 4]);
    __builtin_amdgcn_s_setprio(1);
#pragma unroll
    for (int kt = 0; kt < 6; ++kt) {
      bf16x8 m = (kt == 0) ? ce0 : (kt == 1) ? ce1 : (kt == 2) ? nA0
               : (kt == 3) ? nA1 : (kt == 4) ? nA2 : nA3;
#pragma unroll
      for (int nt = 0; nt < 4; ++nt) {
        bf16x8 w = *reinterpret_cast<const bf16x8*>(wstage + (kt * 4 + nt) * 512 + lane * 8);
        acc[nt] = __builtin_amdgcn_mfma_f32_16x16x32_bf16(w, m, acc[nt], 0, 0, 0);
      }
    }
    __builtin_amdgcn_s_setprio(0);

    // relu -> transpose to B-frag
#pragma unroll
    for (int nt = 0; nt < 4; ++nt) {
      bf16x4 pk;
#pragma unroll
      for (int r = 0; r < 4; ++r) pk[r] = (bf16_t)fmaxf(acc[nt][r], 0.0f);
      *reinterpret_cast<bf16x4*>(&tr[wid][l15][nt * 16 + lg * 4]) = pk;
    }
    bf16x8 hh0 = *reinterpret_cast<const bf16x8*>(&tr[wid][l15][lg * 8]);
    bf16x8 hh1 = *reinterpret_cast<const bf16x8*>(&tr[wid][l15][32 + lg * 8]);

    // layer 2
    f32x4 acc2[4];
#pragma unroll
    for (int nt = 0; nt < 4; ++nt)
      acc2[nt] = *reinterpret_cast<const f32x4*>(&fconst[384 + nt * 16 + lg * 4]);
    __builtin_amdgcn_s_setprio(1);
#pragma unroll
    for (int kt = 0; kt < 2; ++kt)
#pragma unroll
      for (int nt = 0; nt < 4; ++nt) {
        bf16x8 w = *reinterpret_cast<const bf16x8*>(wstage + (24 + kt * 4 + nt) * 512 + lane * 8);
        acc2[nt] = __builtin_amdgcn_mfma_f32_16x16x32_bf16(w, kt ? hh1 : hh0, acc2[nt], 0, 0, 0);
      }
    __builtin_amdgcn_s_setprio(0);

    if constexpr (MODE == 2) {
      // decoder fused; final e never stored
#pragma unroll
      for (int nt = 0; nt < 4; ++nt) {
        bf16x4 pk;
#pragma unroll
        for (int r = 0; r < 4; ++r) pk[r] = (bf16_t)acc2[nt][r];
        *reinterpret_cast<bf16x4*>(&tr[wid][l15][nt * 16 + lg * 4]) = pk;
      }
      bf16x8 eb0 = *reinterpret_cast<const bf16x8*>(&tr[wid][l15][lg * 8]);
      bf16x8 eb1 = *reinterpret_cast<const bf16x8*>(&tr[wid][l15][32 + lg * 8]);
      f32x4 ad[4];
#pragma unroll
      for (int nt = 0; nt < 4; ++nt)
        ad[nt] = *reinterpret_cast<const f32x4*>(&fconst[192 + nt * 16 + lg * 4]);
      __builtin_amdgcn_s_setprio(1);
#pragma unroll
      for (int kt = 0; kt < 2; ++kt)
#pragma unroll
        for (int nt = 0; nt < 4; ++nt) {
          bf16x8 wf = *reinterpret_cast<const bf16x8*>(wstage + (32 + kt * 4 + nt) * 512 + lane * 8);
          ad[nt] = __builtin_amdgcn_mfma_f32_16x16x32_bf16(wf, kt ? eb1 : eb0, ad[nt], 0, 0, 0);
        }
      __builtin_amdgcn_s_setprio(0);
      float s = 0.0f;
#pragma unroll
      for (int nt = 0; nt < 4; ++nt) {
        f32x4 w2 = *reinterpret_cast<const f32x4*>(&fconst[256 + nt * 16 + lg * 4]);
#pragma unroll
        for (int r = 0; r < 4; ++r) s = fmaf(fmaxf(ad[nt][r], 0.0f), w2[r], s);
      }
      s += __shfl_xor(s, 16, 64);
      s += __shfl_xor(s, 32, 64);
      if (lg == 0) {
        float dv = s + b2s;
        out[oA] = (rA >= sA) ? fmaf(alp * nrm, dv, pxA) : 0.0f;
      }
    } else {
      // full-line store: acc2 -> tr -> 2x contiguous 1KB stores (16B/lane)
#pragma unroll
      for (int nt = 0; nt < 4; ++nt) {
        bf16x4 pk;
#pragma unroll
        for (int r = 0; r < 4; ++r) pk[r] = (bf16_t)acc2[nt][r];
        *reinterpret_cast<bf16x4*>(&tr[wid][l15][nt * 16 + lg * 4]) = pk;
      }
      const int rr = lane >> 3, cc = lane & 7;
      bf16x8 w0 = *reinterpret_cast<const bf16x8*>(&tr[wid][rr][cc * 8]);
      bf16x8 w1 = *reinterpret_cast<const bf16x8*>(&tr[wid][8 + rr][cc * 8]);
      *reinterpret_cast<bf16x8*>(e + (size_t)(g * 16 + rr) * 64 + cc * 8) = w0;
      *reinterpret_cast<bf16x8*>(e + (size_t)(g * 16 + 8 + rr) * 64 + cc * 8) = w1;
    }

    // rotate pipeline state
    sA = sB; rA = rB; oA = oB; pxA = pxB;
    eA0 = eB0; eA1 = eB1;
    nA0 = nB0; nA1 = nB1; nA2 = nB2; nA3 = nB3;
    sB = sC; rB = rC; oB = oC; pxB = pxC;
    eB0 = eC0; eB1 = eC1;
  }
}

// ---------------- fused agg + node MLP: block owns 16 nodes ----------------
// 4 waves agg 4 nodes each (identical arithmetic/order to R14's agg_kernel -> bit-identical),
// write bf16 agg to LDS tile; barrier; wave0 runs the 16-node MFMA MLP. Kills the 4MB
// agg buffer round-trip + 4 launches while keeping agg's full 8192-wave parallelism.
__global__ __launch_bounds__(256) void agg_mlp_kernel(
    const bf16_t* __restrict__ e, const int* __restrict__ row_ptr,
    const bf16_t* __restrict__ wfr,  // Wnu1 frags 48-63, Wnu2 frags 64-71
    const float* __restrict__ bnu1, const float* __restrict__ bnu2,
    bf16_t* __restrict__ n_bf) {
  __shared__ alignas(16) bf16_t w2s[8 * 512];  // Wnu2 frags, 8 KB
  __shared__ alignas(16) bf16_t xb[16][72];    // agg tile: 16 nodes x 64 (pitch 72)
  const int tid = threadIdx.x, lane = tid & 63, wid = tid >> 6;
  const int l15 = lane & 15, lg = lane >> 4;
  const int base = blockIdx.x * 16;  // grid 2048 -> 16 nodes/block

  bf16x8 W1r[16];
#pragma unroll
  for (int f = 0; f < 16; ++f)
    W1r[f] = *reinterpret_cast<const bf16x8*>(wfr + (size_t)(48 + f) * 512 + lane * 8);
#pragma unroll
  for (int j = 0; j < 2; ++j)
    reinterpret_cast<bf16x8*>(w2s)[j * 256 + tid] =
        reinterpret_cast<const bf16x8*>(wfr + (size_t)64 * 512)[j * 256 + tid];

  // --- agg: wave wid handles nodes base+wid*4 .. +3 ---
  const int rsub = lane >> 3;
  for (int j = 0; j < 4; ++j) {
    const int node = base + wid * 4 + j;
    const int p0 = row_ptr[node], cnt = row_ptr[node + 1] - p0;
    float a[8] = {0, 0, 0, 0, 0, 0, 0, 0};
    const bf16x8* bb = reinterpret_cast<const bf16x8*>(e + (size_t)p0 * 64) + lane;
    const int nchunk = (cnt + 7) >> 3;
    int c = 0;
    for (; c + 4 <= nchunk; c += 4) {
      bf16x8 v0 = bb[(size_t)(c + 0) * 64];
      bf16x8 v1 = bb[(size_t)(c + 1) * 64];
      bf16x8 v2 = bb[(size_t)(c + 2) * 64];
      bf16x8 v3 = bb[(size_t)(c + 3) * 64];
      {
#pragma unroll
        for (int i = 0; i < 8; ++i) a[i] += (float)v0[i];
#pragma unroll
        for (int i = 0; i < 8; ++i) a[i] += (float)v1[i];
#pragma unroll
        for (int i = 0; i < 8; ++i) a[i] += (float)v2[i];
      }
      if ((c + 3) * 8 + rsub < cnt) {
#pragma unroll
        for (int i = 0; i < 8; ++i) a[i] += (float)v3[i];
      }
    }
    for (; c < nchunk; ++c) {
      bf16x8 v = bb[(size_t)c * 64];
      if (c * 8 + rsub < cnt) {
#pragma unroll
        for (int i = 0; i < 8; ++i) a[i] += (float)v[i];
      }
    }
#pragma unroll
    for (int i = 0; i < 8; ++i) {
      a[i] += __shfl_xor(a[i], 8, 64);
      a[i] += __shfl_xor(a[i], 16, 64);
      a[i] += __shfl_xor(a[i], 32, 64);
    }
    if (lane < 8) {
      bf16x8 pk;
#pragma unroll
      for (int i = 0; i < 8; ++i) pk[i] = (bf16_t)a[i];
      *reinterpret_cast<bf16x8*>(&xb[wid * 4 + j][lane * 8]) = pk;
    }
  }
  __syncthreads();
  if (wid != 0) return;

  // --- MLP for the 16-node tile (wave 0) ---
  f32x4 b1q[4], b2q[4];
#pragma unroll
  for (int nt = 0; nt < 4; ++nt) {
    b1q[nt] = *reinterpret_cast<const f32x4*>(bnu1 + nt * 16 + lg * 4);
    b2q[nt] = *reinterpret_cast<const f32x4*>(bnu2 + nt * 16 + lg * 4);
  }
  bf16x8 xn0 = *reinterpret_cast<const bf16x8*>(n_bf + (size_t)(base + l15) * 64 + lg * 8);
  bf16x8 xn1 = *reinterpret_cast<const bf16x8*>(n_bf + (size_t)(base + l15) * 64 + 32 + lg * 8);
  bf16x8 xa0 = *reinterpret_cast<const bf16x8*>(&xb[l15][lg * 8]);
  bf16x8 xa1 = *reinterpret_cast<const bf16x8*>(&xb[l15][32 + lg * 8]);
  f32x4 acc[4];
#pragma unroll
  for (int nt = 0; nt < 4; ++nt) acc[nt] = b1q[nt];
#pragma unroll
  for (int kt = 0; kt < 4; ++kt) {
    bf16x8 x = (kt == 0) ? xn0 : (kt == 1) ? xn1 : (kt == 2) ? xa0 : xa1;
#pragma unroll
    for (int nt = 0; nt < 4; ++nt)
      acc[nt] = __builtin_amdgcn_mfma_f32_16x16x32_bf16(W1r[kt * 4 + nt], x, acc[nt], 0, 0, 0);
  }
  // xa already in registers -> safe to reuse xb for the hidden transpose
#pragma unroll
  for (int nt = 0; nt < 4; ++nt) {
    bf16x4 pk;
#pragma unroll
    for (int r = 0; r < 4; ++r) pk[r] = (bf16_t)fmaxf(acc[nt][r], 0.0f);
    *reinterpret_cast<bf16x4*>(&xb[l15][nt * 16 + lg * 4]) = pk;
  }
  bf16x8 hh0 = *reinterpret_cast<const bf16x8*>(&xb[l15][lg * 8]);
  bf16x8 hh1 = *reinterpret_cast<const bf16x8*>(&xb[l15][32 + lg * 8]);
  f32x4 acc2[4];
#pragma unroll
  for (int nt = 0; nt < 4; ++nt) acc2[nt] = b2q[nt];
#pragma unroll
  for (int kt = 0; kt < 2; ++kt)
#pragma unroll
    for (int nt = 0; nt < 4; ++nt) {
      bf16x8 w = *reinterpret_cast<const bf16x8*>(w2s + (kt * 4 + nt) * 512 + lane * 8);
      acc2[nt] = __builtin_amdgcn_mfma_f32_16x16x32_bf16(w, kt ? hh1 : hh0, acc2[nt], 0, 0, 0);
    }
#pragma unroll
  for (int nt = 0; nt < 4; ++nt) {
    bf16x4 pk;
#pragma unroll
    for (int r = 0; r < 4; ++r) pk[r] = (bf16_t)acc2[nt][r];
    *reinterpret_cast<bf16x4*>(n_bf + (size_t)(base + l15) * 64 + nt * 16 + lg * 4) = pk;
  }
}

extern "C" void kernel_launch(void* const* d_in, const int* in_sizes, int n_in,
                              void* d_out, int out_size, void* d_ws, size_t ws_size,
                              hipStream_t stream) {
  const float* nodes      = (const float*)d_in[0];
  const float* edges_init = (const float*)d_in[1];
  const int*   receivers  = (const int*)d_in[2];
  const int*   senders    = (const int*)d_in[3];
  const float* Wne1 = (const float*)d_in[4];
  const float* bne1 = (const float*)d_in[5];
  const float* Wne2 = (const float*)d_in[6];
  const float* bne2 = (const float*)d_in[7];
  const float* Wee1 = (const float*)d_in[8];
  const float* bee1 = (const float*)d_in[9];
  const float* Wee2 = (const float*)d_in[10];
  const float* bee2 = (const float*)d_in[11];
  const float* Weu1 = (const float*)d_in[12];
  const float* beu1 = (const float*)d_in[13];
  const float* Weu2 = (const float*)d_in[14];
  const float* beu2 = (const float*)d_in[15];
  const float* Wnu1 = (const float*)d_in[16];
  const float* bnu1 = (const float*)d_in[17];
  const float* Wnu2 = (const float*)d_in[18];
  const float* bnu2 = (const float*)d_in[19];
  const float* Wd1  = (const float*)d_in[20];
  const float* bd1  = (const float*)d_in[21];
  const float* Wd2  = (const float*)d_in[22];
  const float* bd2  = (const float*)d_in[23];
  const float* alpha = (const float*)d_in[24];
  float* out = (float*)d_out;
  (void)in_sizes; (void)n_in; (void)out_size; (void)ws_size;

  char* ws = (char*)d_ws;
  size_t off = 0;
  auto alloc = [&](size_t bytes) -> void* {
    void* p = ws + off;
    off = (off + bytes + 255) & ~(size_t)255;
    return p;
  };
  float*  norm    = (float*)alloc(4);
  u32*    ccur    = (u32*)alloc(sizeof(u32) * 256);
  u32*    bbase   = (u32*)alloc(sizeof(u32) * 256);
  int*    row_ptr = (int*)alloc(sizeof(int) * (NN + 1));
  u16*    bkt_r   = (u16*)alloc(sizeof(u16) * 256 * BCAP);
  u32*    bkt_o   = (u32*)alloc(sizeof(u32) * 256 * BCAP);
  int*    col_idx = (int*)alloc(sizeof(int) * NE);
  int*    s_perm  = (int*)alloc(sizeof(int) * NE);
  int*    r_perm  = (int*)alloc(sizeof(int) * NE);
  float*  x_perm  = (float*)alloc(sizeof(float) * NE);
  bf16_t* n_bf    = (bf16_t*)alloc(sizeof(bf16_t) * (size_t)NN * 64);
  bf16_t* e_buf   = (bf16_t*)alloc(sizeof(bf16_t) * (size_t)NE * 64 + 4096);  // +pad: agg tail overread
  bf16_t* wfr     = (bf16_t*)alloc(sizeof(bf16_t) * 72 * 512);

  hipMemsetAsync(norm, 0, 4, stream);
  hipMemsetAsync(ccur, 0, sizeof(u32) * 256, stream);

  prep_encode_kernel<<<8336, 256, 0, stream>>>(Weu1, Weu2, Wee2, Wd1, Wnu1, Wnu2, wfr,
                                               nodes, Wne1, bne1, Wne2, bne2, n_bf);
  coarse_kernel<<<1024, 256, 0, stream>>>(edges_init, receivers, norm, ccur, bkt_r, bkt_o);
  scan256_kernel<<<1, 256, 0, stream>>>(ccur, bbase, row_ptr);
  bucket_kernel<<<256, 1024, 0, stream>>>(ccur, bbase, bkt_r, bkt_o, senders, edges_init,
                                          row_ptr, col_idx, s_perm, r_perm, x_perm);

  edge_update_kernel<0><<<768, 256, 0, stream>>>(
      e_buf, n_bf, col_idx, s_perm, r_perm, x_perm, wfr, beu1, beu2,
      Wee1, bee1, bee2, norm, bd1, Wd2, bd2, alpha, out);
  for (int t = 1; t <= 4; ++t) {
    agg_mlp_kernel<<<2048, 256, 0, stream>>>(e_buf, row_ptr, wfr, bnu1, bnu2, n_bf);
    if (t < 4)
      edge_update_kernel<1><<<768, 256, 0, stream>>>(
          e_buf, n_bf, col_idx, s_perm, r_perm, x_perm, wfr, beu1, beu2,
          Wee1, bee1, bee2, norm, bd1, Wd2, bd2, alpha, out);
    else
      edge_update_kernel<2><<<768, 256, 0, stream>>>(
          e_buf, n_bf, col_idx, s_perm, r_perm, x_perm, wfr, beu1, beu2,
          Wee1, bee1, bee2, norm, bd1, Wd2, bd2, alpha, out);
  }
}

// Round 16
// 528.013 us; speedup vs baseline: 3.1133x; 1.0204x over previous
//
#include <hip/hip_runtime.h>

#define NN 32768
#define NE 1048576
#define BCAP 5120  // per-bucket capacity; mean 4096, sigma 64 -> 16 sigma headroom

typedef __bf16 bf16_t;
typedef __bf16 bf16x8 __attribute__((ext_vector_type(8)));
typedef __bf16 bf16x4 __attribute__((ext_vector_type(4)));
typedef float f32x4 __attribute__((ext_vector_type(4)));
typedef unsigned int u32;
typedef unsigned short u16;

// ---------------- prologue: weight-frag prep | node encoder ----------------
// wfr layout (72 frags x 512), all 16x16 frags (lane: dim=nt*16+(l&15), k=kt*32+(l>>4)*8+i):
//   0-23 Weu1 | 24-31 Weu2 | 32-39 Wee2 | 40-47 Wd1 | 48-63 Wnu1 (K=128) | 64-71 Wnu2
__global__ __launch_bounds__(256) void prep_encode_kernel(
    const float* __restrict__ Weu1, const float* __restrict__ Weu2,
    const float* __restrict__ Wee2, const float* __restrict__ Wd1,
    const float* __restrict__ Wnu1, const float* __restrict__ Wnu2,
    bf16_t* __restrict__ wfr,
    const float* __restrict__ nodes, const float* __restrict__ Wne1,
    const float* __restrict__ bne1, const float* __restrict__ Wne2,
    const float* __restrict__ bne2, bf16_t* __restrict__ n_bf) {
  const int b = blockIdx.x, tid = threadIdx.x;
  if (b < 144) {
    int idx = b * 256 + tid;  // < 36864 = 72 frags
    int i = idx & 7, lane = (idx >> 3) & 63, f = idx >> 9;
    const float* W;
    int fl;
    if (f < 24)      { W = Weu1; fl = f; }
    else if (f < 32) { W = Weu2; fl = f - 24; }
    else if (f < 40) { W = Wee2; fl = f - 32; }
    else if (f < 48) { W = Wd1;  fl = f - 40; }
    else if (f < 64) { W = Wnu1; fl = f - 48; }
    else             { W = Wnu2; fl = f - 64; }
    int kt = fl >> 2, nt = fl & 3;
    int k = kt * 32 + ((lane >> 4) << 3) + i;
    int col = nt * 16 + (lane & 15);
    wfr[idx] = (bf16_t)W[k * 64 + col];
  } else {
    __shared__ float hs[4][64];
    int wid = tid >> 6, k = tid & 63;
    int node = (b - 144) * 4 + wid;
    float x = nodes[node];
    hs[wid][k] = fmaxf(x * Wne1[k] + bne1[k], 0.0f);
    __syncthreads();
    float acc = bne2[k];
#pragma unroll 8
    for (int j = 0; j < 64; ++j) acc = fmaf(hs[wid][j], Wne2[j * 64 + k], acc);
    n_bf[(size_t)node * 64 + k] = (bf16_t)acc;
  }
}

// ---------------- CSR build, level 1: coarse 256-bucket scatter + absmax ----------------
__global__ __launch_bounds__(256) void coarse_kernel(
    const float* __restrict__ edges_init, const int* __restrict__ recv,
    float* __restrict__ norm, u32* __restrict__ ccur,
    u16* __restrict__ bkt_r, u32* __restrict__ bkt_o) {
  __shared__ u32 hist[256];
  __shared__ u32 base[256];
  __shared__ float mred[4];
  const int tid = threadIdx.x, lane = tid & 63, wid = tid >> 6;
  const int idx = blockIdx.x * 256 + tid;
  hist[tid] = 0;
  __syncthreads();
  int4 r = reinterpret_cast<const int4*>(recv)[idx];
  float4 v = reinterpret_cast<const float4*>(edges_init)[idx];
  float m = fmaxf(fmaxf(fabsf(v.x), fabsf(v.y)), fmaxf(fabsf(v.z), fabsf(v.w)));
#pragma unroll
  for (int off = 32; off > 0; off >>= 1) m = fmaxf(m, __shfl_xor(m, off, 64));
  if (lane == 0) mred[wid] = m;
  atomicAdd(&hist[r.x >> 7], 1u);
  atomicAdd(&hist[r.y >> 7], 1u);
  atomicAdd(&hist[r.z >> 7], 1u);
  atomicAdd(&hist[r.w >> 7], 1u);
  __syncthreads();
  if (tid == 0) {
    float mm = fmaxf(fmaxf(mred[0], mred[1]), fmaxf(mred[2], mred[3]));
    atomicMax(reinterpret_cast<u32*>(norm), __float_as_uint(mm));
  }
  u32 h = hist[tid];
  if (h) base[tid] = atomicAdd(&ccur[tid], h);
  hist[tid] = 0;  // reuse as block-local cursor
  __syncthreads();
  const int e0 = idx * 4;
  int rv4[4] = {r.x, r.y, r.z, r.w};
#pragma unroll
  for (int q = 0; q < 4; ++q) {
    int rv = rv4[q], bk = rv >> 7;
    u32 loc = atomicAdd(&hist[bk], 1u);
    u32 pos = (u32)bk * BCAP + base[bk] + loc;
    bkt_r[pos] = (u16)rv;
    bkt_o[pos] = (u32)(e0 + q);
  }
}

__global__ __launch_bounds__(256) void scan256_kernel(const u32* __restrict__ ccur,
                                                      u32* __restrict__ bbase,
                                                      int* __restrict__ row_ptr) {
  __shared__ u32 s[256];
  const int tid = threadIdx.x;
  s[tid] = ccur[tid];
  __syncthreads();
  if (tid == 0) {
    u32 run = 0;
    for (int j = 0; j < 256; ++j) {
      u32 c = s[j];
      s[j] = run;
      run += c;
    }
    row_ptr[NN] = (int)run;
  }
  __syncthreads();
  bbase[tid] = s[tid];
}

__global__ __launch_bounds__(1024) void bucket_kernel(
    const u32* __restrict__ ccur, const u32* __restrict__ bbase,
    const u16* __restrict__ bkt_r, const u32* __restrict__ bkt_o,
    const int* __restrict__ senders, const float* __restrict__ edges_init,
    int* __restrict__ row_ptr, int* __restrict__ col_idx,
    int* __restrict__ s_perm, int* __restrict__ r_perm, float* __restrict__ x_perm) {
  __shared__ u32 hist[128];
  __shared__ u32 cur[128];
  const int b = blockIdx.x, tid = threadIdx.x;
  const u32 sz = ccur[b], bb = bbase[b];
  if (tid < 128) hist[tid] = 0;
  __syncthreads();
  for (u32 i = tid; i < sz; i += 1024) atomicAdd(&hist[bkt_r[(u32)b * BCAP + i] & 127], 1u);
  __syncthreads();
  if (tid == 0) {
    u32 run = 0;
    for (int j = 0; j < 128; ++j) {
      u32 c = hist[j];
      hist[j] = run;
      cur[j] = run;
      run += c;
    }
  }
  __syncthreads();
  if (tid < 128) row_ptr[b * 128 + tid] = (int)(bb + hist[tid]);
  for (u32 i = tid; i < sz; i += 1024) {
    int rv = (int)bkt_r[(u32)b * BCAP + i];
    int o = (int)bkt_o[(u32)b * BCAP + i];
    u32 loc = atomicAdd(&cur[rv & 127], 1u);
    u32 pos = bb + loc;
    col_idx[pos] = o;
    s_perm[pos] = senders[o];
    r_perm[pos] = rv;
    x_perm[pos] = edges_init[o];
  }
}

// ---------------- mega edge kernel: MODE 0=encode+round0, 1=mid, 2=round4+decode ----------
// R15 operating point + LDS trim: setprio around MFMA clusters (R15: codegen landed on
// VGPR 68, edge 97->77us). LDS now the occupancy binder -> wstage trimmed to W1-only
// (24KB; W2/mode frags from L1-resident global, perf-neutral per R7) -> 4 blocks/CU.
// NO occupancy clamp ever (R4/R10/R13: spills, 4-6x loss).
template <int MODE>
__global__ __launch_bounds__(256) void edge_update_kernel(
    bf16_t* __restrict__ e, const bf16_t* __restrict__ n_bf,
    const int* __restrict__ col_idx,
    const int* __restrict__ s_perm, const int* __restrict__ r_perm,
    const float* __restrict__ x_perm,
    const bf16_t* __restrict__ wfr,
    const float* __restrict__ beu1, const float* __restrict__ beu2,
    const float* __restrict__ Wee1, const float* __restrict__ bee1,
    const float* __restrict__ bee2, const float* __restrict__ norm_p,
    const float* __restrict__ bd1, const float* __restrict__ Wd2,
    const float* __restrict__ bd2_p, const float* __restrict__ alpha_p,
    float* __restrict__ out) {
  __shared__ alignas(16) bf16_t wstage[24 * 512];  // W1 only, 24 KB
  __shared__ alignas(16) bf16_t tr[4][16][72];     // per-wave transpose buffer
  __shared__ alignas(16) float fconst[448];        // Wee1|bee1|bee2|bd1|Wd2|beu1|beu2
  const int tid = threadIdx.x, lane = tid & 63, wid = tid >> 6;
  const int l15 = lane & 15, lg = lane >> 4;

#pragma unroll
  for (int j = 0; j < 6; ++j) {
    int c = j * 256 + tid;  // 1536 chunks of 16B
    int slot = c >> 6, within = c & 63;
    *reinterpret_cast<bf16x8*>(wstage + slot * 512 + within * 8) =
        *reinterpret_cast<const bf16x8*>(wfr + (size_t)slot * 512 + within * 8);
  }
  for (int c = tid; c < 448; c += 256) {
    float v;
    if (c < 64)       v = Wee1[c];
    else if (c < 128) v = bee1[c - 64];
    else if (c < 192) v = bee2[c - 128];
    else if (c < 256) v = bd1[c - 192];
    else if (c < 320) v = Wd2[c - 256];
    else if (c < 384) v = beu1[c - 320];
    else              v = beu2[c - 384];
    fconst[c] = v;
  }
  __syncthreads();  // only block-wide barrier

  const bf16_t* w2g = wfr + (size_t)24 * 512;                     // Weu2 frags (global, L1)
  const bf16_t* wmg = wfr + (size_t)(MODE == 2 ? 40 : 32) * 512;  // Wd1 / Wee2 frags

  float invn = 0.f;
  if constexpr (MODE == 0) invn = 1.0f / *norm_p;
  float nrm = 0.f, alp = 0.f, b2s = 0.f;
  if constexpr (MODE == 2) { nrm = *norm_p; alp = *alpha_p; b2s = *bd2_p; }

  // XCD-aware block swizzle (gridDim.x % 8 == 0)
  const int nb = gridDim.x, cpx = nb >> 3;
  const int bs = (blockIdx.x & 7) * cpx + (blockIdx.x >> 3);
  const int NWAVE = nb * 4;
  const int NG = NE / 16;
  const int g0 = bs * 4 + wid;

  // pipeline state
  int sA, rA, oA, sB, rB, oB, sC, rC, oC;
  float pxA = 0.f, pxB = 0.f, pxC = 0.f;
  bf16x8 eA0, eA1, eB0, eB1, eC0, eC1;
  bf16x8 nA0, nA1, nA2, nA3, nB0, nB1, nB2, nB3;

  auto P1 = [&](int g, int& s, int& r, int& o, float& px, bf16x8& e0, bf16x8& e1) {
    int row = g * 16 + l15;
    s = s_perm[row];
    r = r_perm[row];
    if constexpr (MODE != 1) px = x_perm[row];
    if constexpr (MODE == 2) o = col_idx[row];
    if constexpr (MODE != 0) {
      const bf16x8* er = reinterpret_cast<const bf16x8*>(e + (size_t)row * 64);
      e0 = er[lg];
      e1 = er[4 + lg];
    }
  };
  auto P2 = [&](int s, int r, bf16x8& n0, bf16x8& n1, bf16x8& n2, bf16x8& n3) {
    const bf16x8* sp = reinterpret_cast<const bf16x8*>(n_bf + (size_t)s * 64);
    n0 = sp[lg];
    n1 = sp[4 + lg];
    const bf16x8* rp = reinterpret_cast<const bf16x8*>(n_bf + (size_t)r * 64);
    n2 = rp[lg];
    n3 = rp[4 + lg];
  };

  if (g0 < NG) {
    P1(g0, sA, rA, oA, pxA, eA0, eA1);
    P2(sA, rA, nA0, nA1, nA2, nA3);
    int g1 = g0 + NWAVE;
    if (g1 < NG) P1(g1, sB, rB, oB, pxB, eB0, eB1);
  }

  for (int g = g0; g < NG; g += NWAVE) {
    const int gB = g + NWAVE, gC = g + 2 * NWAVE;
    if (gB < NG) P2(sB, rB, nB0, nB1, nB2, nB3);
    if (gC < NG) P1(gC, sC, rC, oC, pxC, eC0, eC1);

    // === compute on group g ===
    bf16x8 ce0, ce1;
    if constexpr (MODE == 0) {
      float xv = pxA * invn;
      f32x4 wl0 = *reinterpret_cast<const f32x4*>(&fconst[lg * 8]);
      f32x4 wl1 = *reinterpret_cast<const f32x4*>(&fconst[lg * 8 + 4]);
      f32x4 wh0 = *reinterpret_cast<const f32x4*>(&fconst[32 + lg * 8]);
      f32x4 wh1 = *reinterpret_cast<const f32x4*>(&fconst[32 + lg * 8 + 4]);
      f32x4 bl0 = *reinterpret_cast<const f32x4*>(&fconst[64 + lg * 8]);
      f32x4 bl1 = *reinterpret_cast<const f32x4*>(&fconst[64 + lg * 8 + 4]);
      f32x4 bh0 = *reinterpret_cast<const f32x4*>(&fconst[96 + lg * 8]);
      f32x4 bh1 = *reinterpret_cast<const f32x4*>(&fconst[96 + lg * 8 + 4]);
      bf16x8 h0, h1;
#pragma unroll
      for (int i = 0; i < 4; ++i) {
        h0[i]     = (bf16_t)fmaxf(fmaf(xv, wl0[i], bl0[i]), 0.0f);
        h0[4 + i] = (bf16_t)fmaxf(fmaf(xv, wl1[i], bl1[i]), 0.0f);
        h1[i]     = (bf16_t)fmaxf(fmaf(xv, wh0[i], bh0[i]), 0.0f);
        h1[4 + i] = (bf16_t)fmaxf(fmaf(xv, wh1[i], bh1[i]), 0.0f);
      }
      f32x4 ae[4];
#pragma unroll
      for (int nt = 0; nt < 4; ++nt)
        ae[nt] = *reinterpret_cast<const f32x4*>(&fconst[128 + nt * 16 + lg * 4]);
      __builtin_amdgcn_s_setprio(1);
#pragma unroll
      for (int kt = 0; kt < 2; ++kt)
#pragma unroll
        for (int nt = 0; nt < 4; ++nt) {
          bf16x8 wf = *reinterpret_cast<const bf16x8*>(wmg + (size_t)(kt * 4 + nt) * 512 + lane * 8);
          ae[nt] = __builtin_amdgcn_mfma_f32_16x16x32_bf16(wf, kt ? h1 : h0, ae[nt], 0, 0, 0);
        }
      __builtin_amdgcn_s_setprio(0);
#pragma unroll
      for (int nt = 0; nt < 4; ++nt) {
        bf16x4 pk;
#pragma unroll
        for (int r = 0; r < 4; ++r) pk[r] = (bf16_t)ae[nt][r];
        *reinterpret_cast<bf16x4*>(&tr[wid][l15][nt * 16 + lg * 4]) = pk;
      }
      ce0 = *reinterpret_cast<const bf16x8*>(&tr[wid][l15][lg * 8]);
      ce1 = *reinterpret_cast<const bf16x8*>(&tr[wid][l15][32 + lg * 8]);
    } else {
      ce0 = eA0;
      ce1 = eA1;
    }

    // layer 1 (W1 from LDS)
    f32x4 acc[4];
#pragma unroll
    for (int nt = 0; nt < 4; ++nt)
      acc[nt] = *reinterpret_cast<const f32x4*>(&fconst[320 + nt * 16 + lg * 4]);
    __builtin_amdgcn_s_setprio(1);
#pragma unroll
    for (int kt = 0; kt < 6; ++kt) {
      bf16x8 m = (kt == 0) ? ce0 : (kt == 1) ? ce1 : (kt == 2) ? nA0
               : (kt == 3) ? nA1 : (kt == 4) ? nA2 : nA3;
#pragma unroll
      for (int nt = 0; nt < 4; ++nt) {
        bf16x8 w = *reinterpret_cast<const bf16x8*>(wstage + (kt * 4 + nt) * 512 + lane * 8);
        acc[nt] = __builtin_amdgcn_mfma_f32_16x16x32_bf16(w, m, acc[nt], 0, 0, 0);
      }
    }
    __builtin_amdgcn_s_setprio(0);

    // relu -> transpose to B-frag
#pragma unroll
    for (int nt = 0; nt < 4; ++nt) {
      bf16x4 pk;
#pragma unroll
      for (int r = 0; r < 4; ++r) pk[r] = (bf16_t)fmaxf(acc[nt][r], 0.0f);
      *reinterpret_cast<bf16x4*>(&tr[wid][l15][nt * 16 + lg * 4]) = pk;
    }
    bf16x8 hh0 = *reinterpret_cast<const bf16x8*>(&tr[wid][l15][lg * 8]);
    bf16x8 hh1 = *reinterpret_cast<const bf16x8*>(&tr[wid][l15][32 + lg * 8]);

    // layer 2 (W2 from global, L1-resident)
    f32x4 acc2[4];
#pragma unroll
    for (int nt = 0; nt < 4; ++nt)
      acc2[nt] = *reinterpret_cast<const f32x4*>(&fconst[384 + nt * 16 + lg * 4]);
    __builtin_amdgcn_s_setprio(1);
#pragma unroll
    for (int kt = 0; kt < 2; ++kt)
#pragma unroll
      for (int nt = 0; nt < 4; ++nt) {
        bf16x8 w = *reinterpret_cast<const bf16x8*>(w2g + (size_t)(kt * 4 + nt) * 512 + lane * 8);
        acc2[nt] = __builtin_amdgcn_mfma_f32_16x16x32_bf16(w, kt ? hh1 : hh0, acc2[nt], 0, 0, 0);
      }
    __builtin_amdgcn_s_setprio(0);

    if constexpr (MODE == 2) {
      // decoder fused; final e never stored
#pragma unroll
      for (int nt = 0; nt < 4; ++nt) {
        bf16x4 pk;
#pragma unroll
        for (int r = 0; r < 4; ++r) pk[r] = (bf16_t)acc2[nt][r];
        *reinterpret_cast<bf16x4*>(&tr[wid][l15][nt * 16 + lg * 4]) = pk;
      }
      bf16x8 eb0 = *reinterpret_cast<const bf16x8*>(&tr[wid][l15][lg * 8]);
      bf16x8 eb1 = *reinterpret_cast<const bf16x8*>(&tr[wid][l15][32 + lg * 8]);
      f32x4 ad[4];
#pragma unroll
      for (int nt = 0; nt < 4; ++nt)
        ad[nt] = *reinterpret_cast<const f32x4*>(&fconst[192 + nt * 16 + lg * 4]);
      __builtin_amdgcn_s_setprio(1);
#pragma unroll
      for (int kt = 0; kt < 2; ++kt)
#pragma unroll
        for (int nt = 0; nt < 4; ++nt) {
          bf16x8 wf = *reinterpret_cast<const bf16x8*>(wmg + (size_t)(kt * 4 + nt) * 512 + lane * 8);
          ad[nt] = __builtin_amdgcn_mfma_f32_16x16x32_bf16(wf, kt ? eb1 : eb0, ad[nt], 0, 0, 0);
        }
      __builtin_amdgcn_s_setprio(0);
      float s = 0.0f;
#pragma unroll
      for (int nt = 0; nt < 4; ++nt) {
        f32x4 w2 = *reinterpret_cast<const f32x4*>(&fconst[256 + nt * 16 + lg * 4]);
#pragma unroll
        for (int r = 0; r < 4; ++r) s = fmaf(fmaxf(ad[nt][r], 0.0f), w2[r], s);
      }
      s += __shfl_xor(s, 16, 64);
      s += __shfl_xor(s, 32, 64);
      if (lg == 0) {
        float dv = s + b2s;
        out[oA] = (rA >= sA) ? fmaf(alp * nrm, dv, pxA) : 0.0f;
      }
    } else {
      // full-line store: acc2 -> tr -> 2x contiguous 1KB stores (16B/lane)
#pragma unroll
      for (int nt = 0; nt < 4; ++nt) {
        bf16x4 pk;
#pragma unroll
        for (int r = 0; r < 4; ++r) pk[r] = (bf16_t)acc2[nt][r];
        *reinterpret_cast<bf16x4*>(&tr[wid][l15][nt * 16 + lg * 4]) = pk;
      }
      const int rr = lane >> 3, cc = lane & 7;
      bf16x8 w0 = *reinterpret_cast<const bf16x8*>(&tr[wid][rr][cc * 8]);
      bf16x8 w1 = *reinterpret_cast<const bf16x8*>(&tr[wid][8 + rr][cc * 8]);
      *reinterpret_cast<bf16x8*>(e + (size_t)(g * 16 + rr) * 64 + cc * 8) = w0;
      *reinterpret_cast<bf16x8*>(e + (size_t)(g * 16 + 8 + rr) * 64 + cc * 8) = w1;
    }

    // rotate pipeline state
    sA = sB; rA = rB; oA = oB; pxA = pxB;
    eA0 = eB0; eA1 = eB1;
    nA0 = nB0; nA1 = nB1; nA2 = nB2; nA3 = nB3;
    sB = sC; rB = rC; oB = oC; pxB = pxC;
    eB0 = eC0; eB1 = eC1;
  }
}

// ---------------- agg: full-occupancy streaming segment-sum ----------------
__global__ __launch_bounds__(256) void agg_kernel(const bf16_t* __restrict__ e,
                                                  const int* __restrict__ row_ptr,
                                                  bf16_t* __restrict__ agg) {
  const int lane = threadIdx.x & 63, wid = threadIdx.x >> 6;
  const int rsub = lane >> 3;
  const int gw = blockIdx.x * 4 + wid, NWV = gridDim.x * 4;
  for (int node = gw; node < NN; node += NWV) {
    const int p0 = row_ptr[node], cnt = row_ptr[node + 1] - p0;
    float a[8] = {0, 0, 0, 0, 0, 0, 0, 0};
    const bf16x8* bb = reinterpret_cast<const bf16x8*>(e + (size_t)p0 * 64) + lane;
    const int nchunk = (cnt + 7) >> 3;
    int c = 0;
    for (; c + 4 <= nchunk; c += 4) {
      bf16x8 v0 = bb[(size_t)(c + 0) * 64];
      bf16x8 v1 = bb[(size_t)(c + 1) * 64];
      bf16x8 v2 = bb[(size_t)(c + 2) * 64];
      bf16x8 v3 = bb[(size_t)(c + 3) * 64];
      {
#pragma unroll
        for (int i = 0; i < 8; ++i) a[i] += (float)v0[i];
#pragma unroll
        for (int i = 0; i < 8; ++i) a[i] += (float)v1[i];
#pragma unroll
        for (int i = 0; i < 8; ++i) a[i] += (float)v2[i];
      }
      if ((c + 3) * 8 + rsub < cnt) {
#pragma unroll
        for (int i = 0; i < 8; ++i) a[i] += (float)v3[i];
      }
    }
    for (; c < nchunk; ++c) {
      bf16x8 v = bb[(size_t)c * 64];
      if (c * 8 + rsub < cnt) {
#pragma unroll
        for (int i = 0; i < 8; ++i) a[i] += (float)v[i];
      }
    }
#pragma unroll
    for (int i = 0; i < 8; ++i) {
      a[i] += __shfl_xor(a[i], 8, 64);
      a[i] += __shfl_xor(a[i], 16, 64);
      a[i] += __shfl_xor(a[i], 32, 64);
    }
    if (lane < 8) {
      bf16x8 pk;
#pragma unroll
      for (int i = 0; i < 8; ++i) pk[i] = (bf16_t)a[i];
      *reinterpret_cast<bf16x8*>(agg + (size_t)node * 64 + lane * 8) = pk;
    }
  }
}

// ---------------- node MLP via MFMA (16 nodes per wave-task) ----------------
__global__ __launch_bounds__(256) void node_mlp_kernel(
    const bf16_t* __restrict__ agg, const bf16_t* __restrict__ wfr,
    const float* __restrict__ bnu1, const float* __restrict__ bnu2,
    bf16_t* __restrict__ n_bf) {
  __shared__ alignas(16) bf16_t w2s[8 * 512];   // Wnu2 frags (64-71), 8 KB
  __shared__ alignas(16) bf16_t xb[4][16][72];  // per-wave transpose buffer
  const int tid = threadIdx.x, lane = tid & 63, wid = tid >> 6;
  const int l15 = lane & 15, lg = lane >> 4;

  bf16x8 W1r[16];  // Wnu1 frags 48-63 (K=128 -> kt<4, nt<4)
#pragma unroll
  for (int f = 0; f < 16; ++f)
    W1r[f] = *reinterpret_cast<const bf16x8*>(wfr + (size_t)(48 + f) * 512 + lane * 8);
#pragma unroll
  for (int j = 0; j < 2; ++j)
    reinterpret_cast<bf16x8*>(w2s)[j * 256 + tid] =
        reinterpret_cast<const bf16x8*>(wfr + (size_t)64 * 512)[j * 256 + tid];
  __syncthreads();

  f32x4 b1q[4], b2q[4];
#pragma unroll
  for (int nt = 0; nt < 4; ++nt) {
    b1q[nt] = *reinterpret_cast<const f32x4*>(bnu1 + nt * 16 + lg * 4);
    b2q[nt] = *reinterpret_cast<const f32x4*>(bnu2 + nt * 16 + lg * 4);
  }

  const int NT = NN / 16;
  for (int task = blockIdx.x * 4 + wid; task < NT; task += gridDim.x * 4) {
    const int base = task * 16;
    bf16x8 xn0 = *reinterpret_cast<const bf16x8*>(n_bf + (size_t)(base + l15) * 64 + lg * 8);
    bf16x8 xn1 = *reinterpret_cast<const bf16x8*>(n_bf + (size_t)(base + l15) * 64 + 32 + lg * 8);
    bf16x8 xa0 = *reinterpret_cast<const bf16x8*>(agg + (size_t)(base + l15) * 64 + lg * 8);
    bf16x8 xa1 = *reinterpret_cast<const bf16x8*>(agg + (size_t)(base + l15) * 64 + 32 + lg * 8);
    f32x4 acc[4];
#pragma unroll
    for (int nt = 0; nt < 4; ++nt) acc[nt] = b1q[nt];
#pragma unroll
    for (int kt = 0; kt < 4; ++kt) {
      bf16x8 x = (kt == 0) ? xn0 : (kt == 1) ? xn1 : (kt == 2) ? xa0 : xa1;
#pragma unroll
      for (int nt = 0; nt < 4; ++nt)
        acc[nt] = __builtin_amdgcn_mfma_f32_16x16x32_bf16(W1r[kt * 4 + nt], x, acc[nt], 0, 0, 0);
    }
#pragma unroll
    for (int nt = 0; nt < 4; ++nt) {
      bf16x4 pk;
#pragma unroll
      for (int r = 0; r < 4; ++r) pk[r] = (bf16_t)fmaxf(acc[nt][r], 0.0f);
      *reinterpret_cast<bf16x4*>(&xb[wid][l15][nt * 16 + lg * 4]) = pk;
    }
    bf16x8 hh0 = *reinterpret_cast<const bf16x8*>(&xb[wid][l15][lg * 8]);
    bf16x8 hh1 = *reinterpret_cast<const bf16x8*>(&xb[wid][l15][32 + lg * 8]);
    f32x4 acc2[4];
#pragma unroll
    for (int nt = 0; nt < 4; ++nt) acc2[nt] = b2q[nt];
#pragma unroll
    for (int kt = 0; kt < 2; ++kt)
#pragma unroll
      for (int nt = 0; nt < 4; ++nt) {
        bf16x8 w = *reinterpret_cast<const bf16x8*>(w2s + (kt * 4 + nt) * 512 + lane * 8);
        acc2[nt] = __builtin_amdgcn_mfma_f32_16x16x32_bf16(w, kt ? hh1 : hh0, acc2[nt], 0, 0, 0);
      }
#pragma unroll
    for (int nt = 0; nt < 4; ++nt) {
      bf16x4 pk;
#pragma unroll
      for (int r = 0; r < 4; ++r) pk[r] = (bf16_t)acc2[nt][r];
      *reinterpret_cast<bf16x4*>(n_bf + (size_t)(base + l15) * 64 + nt * 16 + lg * 4) = pk;
    }
  }
}

extern "C" void kernel_launch(void* const* d_in, const int* in_sizes, int n_in,
                              void* d_out, int out_size, void* d_ws, size_t ws_size,
                              hipStream_t stream) {
  const float* nodes      = (const float*)d_in[0];
  const float* edges_init = (const float*)d_in[1];
  const int*   receivers  = (const int*)d_in[2];
  const int*   senders    = (const int*)d_in[3];
  const float* Wne1 = (const float*)d_in[4];
  const float* bne1 = (const float*)d_in[5];
  const float* Wne2 = (const float*)d_in[6];
  const float* bne2 = (const float*)d_in[7];
  const float* Wee1 = (const float*)d_in[8];
  const float* bee1 = (const float*)d_in[9];
  const float* Wee2 = (const float*)d_in[10];
  const float* bee2 = (const float*)d_in[11];
  const float* Weu1 = (const float*)d_in[12];
  const float* beu1 = (const float*)d_in[13];
  const float* Weu2 = (const float*)d_in[14];
  const float* beu2 = (const float*)d_in[15];
  const float* Wnu1 = (const float*)d_in[16];
  const float* bnu1 = (const float*)d_in[17];
  const float* Wnu2 = (const float*)d_in[18];
  const float* bnu2 = (const float*)d_in[19];
  const float* Wd1  = (const float*)d_in[20];
  const float* bd1  = (const float*)d_in[21];
  const float* Wd2  = (const float*)d_in[22];
  const float* bd2  = (const float*)d_in[23];
  const float* alpha = (const float*)d_in[24];
  float* out = (float*)d_out;
  (void)in_sizes; (void)n_in; (void)out_size; (void)ws_size;

  char* ws = (char*)d_ws;
  size_t off = 0;
  auto alloc = [&](size_t bytes) -> void* {
    void* p = ws + off;
    off = (off + bytes + 255) & ~(size_t)255;
    return p;
  };
  float*  norm    = (float*)alloc(4);
  u32*    ccur    = (u32*)alloc(sizeof(u32) * 256);
  u32*    bbase   = (u32*)alloc(sizeof(u32) * 256);
  int*    row_ptr = (int*)alloc(sizeof(int) * (NN + 1));
  u16*    bkt_r   = (u16*)alloc(sizeof(u16) * 256 * BCAP);
  u32*    bkt_o   = (u32*)alloc(sizeof(u32) * 256 * BCAP);
  int*    col_idx = (int*)alloc(sizeof(int) * NE);
  int*    s_perm  = (int*)alloc(sizeof(int) * NE);
  int*    r_perm  = (int*)alloc(sizeof(int) * NE);
  float*  x_perm  = (float*)alloc(sizeof(float) * NE);
  bf16_t* n_bf    = (bf16_t*)alloc(sizeof(bf16_t) * (size_t)NN * 64);
  bf16_t* agg     = (bf16_t*)alloc(sizeof(bf16_t) * (size_t)NN * 64);
  bf16_t* e_buf   = (bf16_t*)alloc(sizeof(bf16_t) * (size_t)NE * 64 + 4096);  // +pad: agg tail overread
  bf16_t* wfr     = (bf16_t*)alloc(sizeof(bf16_t) * 72 * 512);

  hipMemsetAsync(norm, 0, 4, stream);
  hipMemsetAsync(ccur, 0, sizeof(u32) * 256, stream);

  prep_encode_kernel<<<8336, 256, 0, stream>>>(Weu1, Weu2, Wee2, Wd1, Wnu1, Wnu2, wfr,
                                               nodes, Wne1, bne1, Wne2, bne2, n_bf);
  coarse_kernel<<<1024, 256, 0, stream>>>(edges_init, receivers, norm, ccur, bkt_r, bkt_o);
  scan256_kernel<<<1, 256, 0, stream>>>(ccur, bbase, row_ptr);
  bucket_kernel<<<256, 1024, 0, stream>>>(ccur, bbase, bkt_r, bkt_o, senders, edges_init,
                                          row_ptr, col_idx, s_perm, r_perm, x_perm);

  edge_update_kernel<0><<<1024, 256, 0, stream>>>(
      e_buf, n_bf, col_idx, s_perm, r_perm, x_perm, wfr, beu1, beu2,
      Wee1, bee1, bee2, norm, bd1, Wd2, bd2, alpha, out);
  for (int t = 1; t <= 4; ++t) {
    agg_kernel<<<2048, 256, 0, stream>>>(e_buf, row_ptr, agg);
    node_mlp_kernel<<<512, 256, 0, stream>>>(agg, wfr, bnu1, bnu2, n_bf);
    if (t < 4)
      edge_update_kernel<1><<<1024, 256, 0, stream>>>(
          e_buf, n_bf, col_idx, s_perm, r_perm, x_perm, wfr, beu1, beu2,
          Wee1, bee1, bee2, norm, bd1, Wd2, bd2, alpha, out);
    else
      edge_update_kernel<2><<<1024, 256, 0, stream>>>(
          e_buf, n_bf, col_idx, s_perm, r_perm, x_perm, wfr, beu1, beu2,
          Wee1, bee1, bee2, norm, bd1, Wd2, bd2, alpha, out);
  }
}